// Round 15
// baseline (280.487 us; speedup 1.0000x reference)
//
#include <hip/hip_runtime.h>
#include <math.h>

#define D_MODEL 384
#define HEADS 8
#define DIM_HEAD 48
#define NTOK 1024
#define BATCH 8
#define D_FF 1536
#define LN_EPS 1e-5f

typedef unsigned short u16;
typedef unsigned int u32;
typedef unsigned long long u64;
typedef short short8 __attribute__((ext_vector_type(8)));
typedef float f32x4 __attribute__((ext_vector_type(4)));

union F8 { short8 v; u64 q[2]; u16 u[8]; uint4 u4; };

__device__ __forceinline__ u16 f2bf(float f) {
    union { float f; unsigned u; } c; c.f = f;
    unsigned r = c.u + 0x7FFFu + ((c.u >> 16) & 1u);
    return (u16)(r >> 16);
}
__device__ __forceinline__ float bf2f(u16 u) {
    union { unsigned u; float f; } c; c.u = ((unsigned)u) << 16; return c.f;
}
__device__ __forceinline__ void gload_lds16(const u16* g, u16* l) {
    __builtin_amdgcn_global_load_lds(
        (const __attribute__((address_space(1))) void*)g,
        (__attribute__((address_space(3))) void*)l, 16, 0, 0);
}

// ---------------- add + cast (QKin = bf16(src+pos), SRCB = bf16(src)) ----------------
__global__ __launch_bounds__(256) void add_cast_kernel(
        const float4* __restrict__ a, const float4* __restrict__ b,
        ushort4* __restrict__ o1, ushort4* __restrict__ o2, int n4) {
    int i = blockIdx.x * blockDim.x + threadIdx.x;
    if (i >= n4) return;
    float4 x = a[i], y = b[i];
    ushort4 u1, u2;
    u1.x = f2bf(x.x + y.x); u1.y = f2bf(x.y + y.y); u1.z = f2bf(x.z + y.z); u1.w = f2bf(x.w + y.w);
    u2.x = f2bf(x.x); u2.y = f2bf(x.y); u2.z = f2bf(x.z); u2.w = f2bf(x.w);
    o1[i] = u1; o2[i] = u2;
}

// ---------------- 4x square transpose + cast (384x384), z-batched ----------------
__global__ __launch_bounds__(256) void castT4_kernel(
        const float* __restrict__ i0, const float* __restrict__ i1,
        const float* __restrict__ i2, const float* __restrict__ i3,
        u16* __restrict__ o0, u16* __restrict__ o1,
        u16* __restrict__ o2, u16* __restrict__ o3) {
    const float* in  = (blockIdx.z == 0) ? i0 : (blockIdx.z == 1) ? i1 : (blockIdx.z == 2) ? i2 : i3;
    u16*         out = (blockIdx.z == 0) ? o0 : (blockIdx.z == 1) ? o1 : (blockIdx.z == 2) ? o2 : o3;
    __shared__ float t[32][33];
    int c0 = blockIdx.x * 32, r0 = blockIdx.y * 32;
    int tx = threadIdx.x, ty = threadIdx.y;  // 32 x 8
    for (int i = ty; i < 32; i += 8)
        t[i][tx] = in[(long)(r0 + i) * 384 + c0 + tx];
    __syncthreads();
    for (int i = ty; i < 32; i += 8)
        out[(long)(c0 + i) * 384 + r0 + tx] = f2bf(t[tx][i]);
}

// ---------------- transpose + cast: out[c][r] = bf16(in[r][c]) ----------------
__global__ __launch_bounds__(256) void castT_kernel(
        const float* __restrict__ in, u16* __restrict__ out, int R, int C) {
    __shared__ float t[32][33];
    int c0 = blockIdx.x * 32, r0 = blockIdx.y * 32;
    int tx = threadIdx.x, ty = threadIdx.y;  // 32 x 8
    for (int i = ty; i < 32; i += 8)
        t[i][tx] = in[(long)(r0 + i) * C + c0 + tx];
    __syncthreads();
    for (int i = ty; i < 32; i += 8)
        out[(long)(c0 + i) * R + r0 + tx] = f2bf(t[tx][i]);
}

// ---------------- relative bias, transposed, bf16: BT[h][n][m] = bias[h][m][n] ----------------
__global__ __launch_bounds__(256) void biasT_bf16_kernel(const float* __restrict__ table,
                                                         u16* __restrict__ BT) {
    long i = (long)blockIdx.x * blockDim.x + threadIdx.x;
    const long total = (long)HEADS * NTOK * NTOK;
    if (i >= total) return;
    int m = (int)(i & 1023);
    int n = (int)((i >> 10) & 1023);
    int h = (int)(i >> 20);
    int dy = (m >> 5) - (n >> 5) + 31;
    int dx = (m & 31) - (n & 31) + 31;
    BT[i] = f2bf(table[(dy * 63 + dx) * HEADS + h]);
}

// ---------------- MFMA GEMM, 128x128 tile, double-buffered global_load_lds ----------------
// Counted-vmcnt pipeline with sched_barrier(0) pins: raw s_barrier is NOT a compiler
// memory fence, so every region boundary is pinned to stop DMA-issue hoisting (R14 race).
template<int OUTMODE, bool HAS_BIAS, bool HAS_RES, bool GELU_>
__global__ __launch_bounds__(256) void mgemm128_kernel(
        const u16* __restrict__ Ab, const u16* __restrict__ Btb,
        float* __restrict__ Cf, u16* __restrict__ Cb, u16* __restrict__ Ct,
        const float* __restrict__ bias, const float* __restrict__ Rb,
        int Kd, int lda, int ldbt, int ldc, int ldr) {
    __shared__ u16 As[2][128 * 32];
    __shared__ u16 Bs[2][128 * 32];
    int tid = threadIdx.x, wave = tid >> 6, lane = tid & 63, g = lane >> 4, l15 = lane & 15;
    int wm = wave >> 1, wn = wave & 1;
    int row0 = blockIdx.y * 128, col0 = blockIdx.x * 128;

    f32x4 acc[4][4] = {};

    int sr = lane >> 2, sk = lane & 3;
    const u16* aG0 = Ab  + (long)(row0 + wave * 16 + sr) * lda  + sk * 8;
    const u16* aG1 = Ab  + (long)(row0 + (wave + 4) * 16 + sr) * lda  + sk * 8;
    const u16* bG0 = Btb + (long)(col0 + wave * 16 + sr) * ldbt + sk * 8;
    const u16* bG1 = Btb + (long)(col0 + (wave + 4) * 16 + sr) * ldbt + sk * 8;
    int w0off = (wave * 16) * 32, w1off = ((wave + 4) * 16) * 32;

    const int T = Kd >> 5;
    gload_lds16(aG0, &As[0][w0off]);
    gload_lds16(aG1, &As[0][w1off]);
    gload_lds16(bG0, &Bs[0][w0off]);
    gload_lds16(bG1, &Bs[0][w1off]);
    __builtin_amdgcn_sched_barrier(0);

    for (int t = 0; t < T; ++t) {
        int cur = t & 1, nxt = cur ^ 1;
        if (t + 1 < T) {
            int k1 = (t + 1) << 5;
            gload_lds16(aG0 + k1, &As[nxt][w0off]);
            gload_lds16(aG1 + k1, &As[nxt][w1off]);
            gload_lds16(bG0 + k1, &Bs[nxt][w0off]);
            gload_lds16(bG1 + k1, &Bs[nxt][w1off]);
            __builtin_amdgcn_sched_barrier(0);
            asm volatile("s_waitcnt vmcnt(4)" ::: "memory");  // tile t landed; t+1 in flight
        } else {
            asm volatile("s_waitcnt vmcnt(0)" ::: "memory");
        }
        __builtin_amdgcn_sched_barrier(0);
        __builtin_amdgcn_s_barrier();
        __builtin_amdgcn_sched_barrier(0);
        F8 af[4], bfr[4];
#pragma unroll
        for (int fm = 0; fm < 4; ++fm)
            af[fm].u4 = *(const uint4*)&As[cur][(wm * 64 + fm * 16 + l15) * 32 + g * 8];
#pragma unroll
        for (int fn = 0; fn < 4; ++fn)
            bfr[fn].u4 = *(const uint4*)&Bs[cur][(wn * 64 + fn * 16 + l15) * 32 + g * 8];
#pragma unroll
        for (int fm = 0; fm < 4; ++fm)
#pragma unroll
            for (int fn = 0; fn < 4; ++fn)
                acc[fm][fn] = __builtin_amdgcn_mfma_f32_16x16x32_bf16(
                    af[fm].v, bfr[fn].v, acc[fm][fn], 0, 0, 0);
        __builtin_amdgcn_sched_barrier(0);
        __builtin_amdgcn_s_barrier();   // all waves done reading buf[cur] before re-stage
        __builtin_amdgcn_sched_barrier(0);
    }

#pragma unroll
    for (int fm = 0; fm < 4; ++fm) {
        int rbase = row0 + wm * 64 + fm * 16 + g * 4;
#pragma unroll
        for (int fn = 0; fn < 4; ++fn) {
            int c = col0 + wn * 64 + fn * 16 + l15;
            float bv = HAS_BIAS ? bias[c] : 0.f;
            float vs[4];
#pragma unroll
            for (int r = 0; r < 4; ++r) {
                float v = acc[fm][fn][r] + bv;
                if (HAS_RES) v += Rb[(long)(rbase + r) * ldr + c];
                if (GELU_)   v = 0.5f * v * (1.f + erff(v * 0.70710678118654752f));
                vs[r] = v;
                if (OUTMODE & 1) Cf[(long)(rbase + r) * ldc + c] = v;
                if (OUTMODE & 2) Cb[(long)(rbase + r) * ldc + c] = f2bf(v);
            }
            if (OUTMODE & 8) {
                int hh2 = (c * 683) >> 15; int dd = c - hh2 * 48;   // valid for c < 768
                int bb2 = rbase >> 10;     int mm = rbase & 1023;
                ushort4 o;
                o.x = f2bf(vs[0]); o.y = f2bf(vs[1]); o.z = f2bf(vs[2]); o.w = f2bf(vs[3]);
                *(ushort4*)&Ct[(long)hh2 * 393216 + (long)(bb2 * 48 + dd) * 1024 + mm] = o;
            }
        }
    }
}

// ---------------- fused bias matmuls -> MFMA-fragment-tiled Q/K/V ----------------
// 1D grid 768, XCD-swizzled (one head per XCD). Double-buffered staging, pinned regions.
__global__ __launch_bounds__(256) void bias3_kernel(
        const u16* __restrict__ BT, const u16* __restrict__ QtH,
        const u16* __restrict__ KtH, const u16* __restrict__ VtH,
        u16* __restrict__ Q2H, u16* __restrict__ K2H, u16* __restrict__ V2T) {
    int bid = blockIdx.x;
    int widx = (bid & 7) * 96 + (bid >> 3);   // bijective (768 % 8 == 0)
    int h = widx / 96;
    int rem = widx - h * 96;
    int ry = rem / 6, cx = rem - ry * 6;
    const long hb = (long)h * 393216;
    const u16* A = BT + (long)h * 1048576;
    __shared__ u16 As[2][64 * 32];
    __shared__ u16 Bq[2][64 * 32], Bk[2][64 * 32], Bv[2][64 * 32];
    int tid = threadIdx.x, wave = tid >> 6, lane = tid & 63, g = lane >> 4, l15 = lane & 15;
    int wm = wave >> 1, wn = wave & 1;
    int row0 = ry * 64, col0 = cx * 64;
    f32x4 acc[3][2][2] = {};

    int sr = lane >> 2, sk = lane & 3;
    const u16* aG = A   + (long)(row0 + wave * 16 + sr) * 1024 + sk * 8;
    const u16* qG = QtH + hb + (long)(col0 + wave * 16 + sr) * 1024 + sk * 8;
    const u16* kG = KtH + hb + (long)(col0 + wave * 16 + sr) * 1024 + sk * 8;
    const u16* vG = VtH + hb + (long)(col0 + wave * 16 + sr) * 1024 + sk * 8;
    int woff = (wave * 16) * 32;

    gload_lds16(aG, &As[0][woff]);
    gload_lds16(qG, &Bq[0][woff]);
    gload_lds16(kG, &Bk[0][woff]);
    gload_lds16(vG, &Bv[0][woff]);
    __builtin_amdgcn_sched_barrier(0);

    for (int t = 0; t < 32; ++t) {
        int cur = t & 1, nxt = cur ^ 1;
        if (t + 1 < 32) {
            int k1 = (t + 1) << 5;
            gload_lds16(aG + k1, &As[nxt][woff]);
            gload_lds16(qG + k1, &Bq[nxt][woff]);
            gload_lds16(kG + k1, &Bk[nxt][woff]);
            gload_lds16(vG + k1, &Bv[nxt][woff]);
            __builtin_amdgcn_sched_barrier(0);
            asm volatile("s_waitcnt vmcnt(4)" ::: "memory");
        } else {
            asm volatile("s_waitcnt vmcnt(0)" ::: "memory");
        }
        __builtin_amdgcn_sched_barrier(0);
        __builtin_amdgcn_s_barrier();
        __builtin_amdgcn_sched_barrier(0);
        F8 af0, af1, b0, b1;
        af0.u4 = *(const uint4*)&As[cur][(wm * 32 + l15) * 32 + g * 8];
        af1.u4 = *(const uint4*)&As[cur][(wm * 32 + 16 + l15) * 32 + g * 8];
        // Q
        b0.u4 = *(const uint4*)&Bq[cur][(wn * 32 + l15) * 32 + g * 8];
        b1.u4 = *(const uint4*)&Bq[cur][(wn * 32 + 16 + l15) * 32 + g * 8];
        acc[0][0][0] = __builtin_amdgcn_mfma_f32_16x16x32_bf16(af0.v, b0.v, acc[0][0][0], 0, 0, 0);
        acc[0][0][1] = __builtin_amdgcn_mfma_f32_16x16x32_bf16(af0.v, b1.v, acc[0][0][1], 0, 0, 0);
        acc[0][1][0] = __builtin_amdgcn_mfma_f32_16x16x32_bf16(af1.v, b0.v, acc[0][1][0], 0, 0, 0);
        acc[0][1][1] = __builtin_amdgcn_mfma_f32_16x16x32_bf16(af1.v, b1.v, acc[0][1][1], 0, 0, 0);
        // K
        b0.u4 = *(const uint4*)&Bk[cur][(wn * 32 + l15) * 32 + g * 8];
        b1.u4 = *(const uint4*)&Bk[cur][(wn * 32 + 16 + l15) * 32 + g * 8];
        acc[1][0][0] = __builtin_amdgcn_mfma_f32_16x16x32_bf16(af0.v, b0.v, acc[1][0][0], 0, 0, 0);
        acc[1][0][1] = __builtin_amdgcn_mfma_f32_16x16x32_bf16(af0.v, b1.v, acc[1][0][1], 0, 0, 0);
        acc[1][1][0] = __builtin_amdgcn_mfma_f32_16x16x32_bf16(af1.v, b0.v, acc[1][1][0], 0, 0, 0);
        acc[1][1][1] = __builtin_amdgcn_mfma_f32_16x16x32_bf16(af1.v, b1.v, acc[1][1][1], 0, 0, 0);
        // V
        b0.u4 = *(const uint4*)&Bv[cur][(wn * 32 + l15) * 32 + g * 8];
        b1.u4 = *(const uint4*)&Bv[cur][(wn * 32 + 16 + l15) * 32 + g * 8];
        acc[2][0][0] = __builtin_amdgcn_mfma_f32_16x16x32_bf16(af0.v, b0.v, acc[2][0][0], 0, 0, 0);
        acc[2][0][1] = __builtin_amdgcn_mfma_f32_16x16x32_bf16(af0.v, b1.v, acc[2][0][1], 0, 0, 0);
        acc[2][1][0] = __builtin_amdgcn_mfma_f32_16x16x32_bf16(af1.v, b0.v, acc[2][1][0], 0, 0, 0);
        acc[2][1][1] = __builtin_amdgcn_mfma_f32_16x16x32_bf16(af1.v, b1.v, acc[2][1][1], 0, 0, 0);
        __builtin_amdgcn_sched_barrier(0);
        __builtin_amdgcn_s_barrier();
        __builtin_amdgcn_sched_barrier(0);
    }

    // Q pre-scale: 48^-0.5 * log2(e)  (attention softmax runs in exp2 domain)
    const float qsc = 0.14433756729740643f * 1.4426950408889634f;
#pragma unroll
    for (int fm = 0; fm < 2; ++fm) {
        int rbase = row0 + wm * 32 + fm * 16 + g * 4;  // token (n for Q/K, m for V)
#pragma unroll
        for (int fn = 0; fn < 2; ++fn) {
            int c = col0 + wn * 32 + fn * 16 + l15;    // 0..383 = b*48+d
            int b2 = (c * 683) >> 15, d = c - b2 * 48;
            long bh = (long)h * 8 + b2;
            ushort4 rq = *(const ushort4*)&QtH[hb + (long)c * 1024 + rbase];
            ushort4 rk = *(const ushort4*)&KtH[hb + (long)c * 1024 + rbase];
            ushort4 rv = *(const ushort4*)&VtH[hb + (long)c * 1024 + rbase];
            const u16* rqa = (const u16*)&rq;
            const u16* rka = (const u16*)&rk;
            const u16* rva = (const u16*)&rv;
            int ks = d >> 5, g3 = (d >> 3) & 3, e = d & 7;
            long qbase = ((bh * 64 + (rbase >> 4)) * 8 + ks * 4 + g3) * 128
                       + (rbase & 15) * 8 + e;
            ushort4 vo;
            u16* voa = (u16*)&vo;
#pragma unroll
            for (int r = 0; r < 4; ++r) {
                float qv = acc[0][fm][fn][r] + bf2f(rqa[r]);
                Q2H[qbase + r * 8] = f2bf(qv * qsc);
                float kv = acc[1][fm][fn][r] + bf2f(rka[r]);
                K2H[qbase + r * 8] = f2bf(kv);
                voa[r] = f2bf(acc[2][fm][fn][r] + bf2f(rva[r]));
            }
            long vaddr = ((((bh * 16 + (rbase >> 6)) * 3 + (d >> 4)) * 2
                          + ((rbase >> 5) & 1)) * 4 + ((rbase >> 3) & 3)) * 128
                       + (d & 15) * 8 + (rbase & 7);
            *(ushort4*)&V2T[vaddr] = vo;
            if (d < 16) {
                long pbase = ((bh * 64 + (rbase >> 4)) * 8 + 4 + 2 + (d >> 3)) * 128
                           + (rbase & 15) * 8 + (d & 7);
#pragma unroll
                for (int r = 0; r < 4; ++r) {
                    Q2H[pbase + r * 8] = 0;
                    K2H[pbase + r * 8] = 0;
                }
            }
        }
    }
}

// ---------------- flash attention, MFMA, bf16, wave-split KV, fragment-tiled ----------------
// 1D grid 4096 XCD-swizzled; __launch_bounds__(256,8) -> up to 8 blocks/CU for latency hiding.
__global__ __launch_bounds__(256, 8) void attn_mfma_kernel(
        const u16* __restrict__ Q2H, const u16* __restrict__ K2H,
        const u16* __restrict__ V2T, u16* __restrict__ O) {
    int bid = blockIdx.x;
    int widx = (bid & 7) * 512 + (bid >> 3);   // bijective (4096 % 8 == 0)
    int qb = widx & 63;
    int h  = (widx >> 6) & 7;
    int b  = widx >> 9;
    int tid = threadIdx.x, wave = tid >> 6, lane = tid & 63, g = lane >> 4, l15 = lane & 15;

    __shared__ char smem[13824];
    u16   (*Pl)[16][72]  = (u16(*)[16][72])smem;            // [4][16][72] u16 = 9216 B
    float (*Oc)[16][52]  = (float(*)[16][52])smem;          // [4][16][52] f32 = 13312 B
    float (*MLc)[16][2]  = (float(*)[16][2])(smem + 13312); // 512 B
    const int sw = ((l15 >> 3) & 1) << 5;
    const int loff = (g * 16 + l15) * 8;   // fragment lane offset (u16)

    const long bh = (long)(h * 8 + b);
    const u16* qtile = Q2H + (bh * 64 + qb) * 1024;
    F8 qf0, qf1;
    qf0.u4 = *(const uint4*)(qtile + loff);
    qf1.u4 = *(const uint4*)(qtile + 512 + loff);

    f32x4 oacc[3] = {};
    float runm = -1e30f, runl = 0.f;

#pragma unroll
    for (int it = 0; it < 4; ++it) {
        // ---- QK^T for this wave's 64 keys (4 key-tiles of 16) ----
        f32x4 s[4] = {};
#pragma unroll
        for (int mt = 0; mt < 4; ++mt) {
            const u16* ktile = K2H + (bh * 64 + wave * 16 + it * 4 + mt) * 1024;
            F8 kf0, kf1;
            kf0.u4 = *(const uint4*)(ktile + loff);
            kf1.u4 = *(const uint4*)(ktile + 512 + loff);
            s[mt] = __builtin_amdgcn_mfma_f32_16x16x32_bf16(kf0.v, qf0.v, s[mt], 0, 0, 0);
            s[mt] = __builtin_amdgcn_mfma_f32_16x16x32_bf16(kf1.v, qf1.v, s[mt], 0, 0, 0);
        }

        // ---- V fragments (independent; latency hides under softmax) ----
        const u16* vtile = V2T + (bh * 16 + wave * 4 + it) * 3072;
        F8 vf[3][2];
#pragma unroll
        for (int dt = 0; dt < 3; ++dt)
#pragma unroll
            for (int ks = 0; ks < 2; ++ks)
                vf[dt][ks].u4 = *(const uint4*)(vtile + (dt * 2 + ks) * 512 + loff);

        // ---- online softmax (exp2 domain; scale*log2e pre-folded into Q) ----
        float p[16];
#pragma unroll
        for (int i = 0; i < 16; ++i) p[i] = s[i >> 2][i & 3];
        float pm[8];
#pragma unroll
        for (int i = 0; i < 8; ++i) pm[i] = fmaxf(p[i], p[i + 8]);
#pragma unroll
        for (int st = 4; st > 0; st >>= 1)
#pragma unroll
            for (int i = 0; i < st; ++i) pm[i] = fmaxf(pm[i], pm[i + st]);
        float tmax = pm[0];
        tmax = fmaxf(tmax, __shfl_xor(tmax, 16));
        tmax = fmaxf(tmax, __shfl_xor(tmax, 32));
        if (!__all(tmax <= runm + 8.0f)) {     // defer-max (T13)
            float nm = fmaxf(runm, tmax);
            float corr = __builtin_amdgcn_exp2f(runm - nm);
            runm = nm; runl *= corr;
#pragma unroll
            for (int dt = 0; dt < 3; ++dt) {
                oacc[dt][0] *= corr; oacc[dt][1] *= corr;
                oacc[dt][2] *= corr; oacc[dt][3] *= corr;
            }
        }
        float ps = 0.f;
#pragma unroll
        for (int i = 0; i < 16; ++i) { p[i] = __builtin_amdgcn_exp2f(p[i] - runm); ps += p[i]; }
        ps += __shfl_xor(ps, 16);
        ps += __shfl_xor(ps, 32);
        runl += ps;

        // ---- P -> bf16 -> per-wave LDS redistribution ----
#pragma unroll
        for (int mt = 0; mt < 4; ++mt) {
            u32 wa, wb;
            asm("v_cvt_pk_bf16_f32 %0, %1, %2" : "=v"(wa) : "v"(p[mt * 4]), "v"(p[mt * 4 + 1]));
            asm("v_cvt_pk_bf16_f32 %0, %1, %2" : "=v"(wb) : "v"(p[mt * 4 + 2]), "v"(p[mt * 4 + 3]));
            *(u64*)&Pl[wave][l15][(mt * 16 + g * 4) ^ sw] = ((u64)wb << 32) | wa;
        }
        F8 pb[2];
#pragma unroll
        for (int ks = 0; ks < 2; ++ks) {
            pb[ks].q[0] = *(const u64*)&Pl[wave][l15][(ks * 32 + g * 8) ^ sw];
            pb[ks].q[1] = *(const u64*)&Pl[wave][l15][((ks * 32 + g * 8) + 4) ^ sw];
        }

        // ---- PV ----
#pragma unroll
        for (int dt = 0; dt < 3; ++dt) {
            oacc[dt] = __builtin_amdgcn_mfma_f32_16x16x32_bf16(vf[dt][0].v, pb[0].v, oacc[dt], 0, 0, 0);
            oacc[dt] = __builtin_amdgcn_mfma_f32_16x16x32_bf16(vf[dt][1].v, pb[1].v, oacc[dt], 0, 0, 0);
        }
    }

    // ---- cross-wave combine ----
    __syncthreads();   // all waves done with Pl (unioned with Oc)
#pragma unroll
    for (int dt = 0; dt < 3; ++dt)
#pragma unroll
        for (int r = 0; r < 4; ++r)
            Oc[wave][l15][dt * 16 + g * 4 + r] = oacc[dt][r];
    if (g == 0) { MLc[wave][l15][0] = runm; MLc[wave][l15][1] = runl; }
    __syncthreads();

    if (wave == 0) {
        float mm[4], cc[4];
#pragma unroll
        for (int w = 0; w < 4; ++w) mm[w] = MLc[w][l15][0];
        float M = fmaxf(fmaxf(mm[0], mm[1]), fmaxf(mm[2], mm[3]));
        float LL = 0.f;
#pragma unroll
        for (int w = 0; w < 4; ++w) {
            cc[w] = __builtin_amdgcn_exp2f(mm[w] - M);
            LL += cc[w] * MLc[w][l15][1];
        }
        float inv = 1.f / LL;
        u16* op = O + ((long)b * NTOK + qb * 16 + l15) * D_MODEL + h * DIM_HEAD;
#pragma unroll
        for (int dt = 0; dt < 3; ++dt) {
            ushort4 o;
#pragma unroll
            for (int r = 0; r < 4; ++r) {
                int d = dt * 16 + g * 4 + r;
                float v = cc[0] * Oc[0][l15][d] + cc[1] * Oc[1][l15][d]
                        + cc[2] * Oc[2][l15][d] + cc[3] * Oc[3][l15][d];
                ((u16*)&o)[r] = f2bf(v * inv);
            }
            *(ushort4*)(op + dt * 16 + g * 4) = o;
        }
    }
}

// ---------------- layernorm (+optional residual, optional bf16 copy) ----------------
__global__ __launch_bounds__(128) void ln_kernel(
        const float* __restrict__ X, const float* __restrict__ Rb,
        const float* __restrict__ g, const float* __restrict__ be,
        float* __restrict__ O, u16* __restrict__ Obf, int hasRes) {
    int row = blockIdx.x;
    int tid = threadIdx.x;
    const float* x = X + (long)row * D_MODEL;
    float v[3];
#pragma unroll
    for (int l = 0; l < 3; ++l) {
        int c = tid + l * 128;
        v[l] = x[c];
        if (hasRes) v[l] += Rb[(long)row * D_MODEL + c];
    }
    __shared__ float red[128];
    float s = v[0] + v[1] + v[2];
    red[tid] = s; __syncthreads();
    for (int st = 64; st > 0; st >>= 1) {
        if (tid < st) red[tid] += red[tid + st];
        __syncthreads();
    }
    float mean = red[0] * (1.f / 384.f);
    __syncthreads();
    float sq = 0.f;
#pragma unroll
    for (int l = 0; l < 3; ++l) { float d = v[l] - mean; sq += d * d; }
    red[tid] = sq; __syncthreads();
    for (int st = 64; st > 0; st >>= 1) {
        if (tid < st) red[tid] += red[tid + st];
        __syncthreads();
    }
    float rstd = rsqrtf(red[0] * (1.f / 384.f) + LN_EPS);
#pragma unroll
    for (int l = 0; l < 3; ++l) {
        int c = tid + l * 128;
        float o = (v[l] - mean) * rstd * g[c] + be[c];
        O[(long)row * D_MODEL + c] = o;
        if (Obf) Obf[(long)row * D_MODEL + c] = f2bf(o);
    }
}

extern "C" void kernel_launch(void* const* d_in, const int* in_sizes, int n_in,
                              void* d_out, int out_size, void* d_ws, size_t ws_size,
                              hipStream_t stream) {
    const float* src   = (const float*)d_in[0];
    const float* pos   = (const float*)d_in[1];
    const float* table = (const float*)d_in[2];
    const float* Wq  = (const float*)d_in[3];
    const float* Wk  = (const float*)d_in[4];
    const float* Wv  = (const float*)d_in[5];
    const float* Wo  = (const float*)d_in[6];
    const float* bo  = (const float*)d_in[7];
    const float* W1  = (const float*)d_in[8];
    const float* b1  = (const float*)d_in[9];
    const float* W2  = (const float*)d_in[10];
    const float* b2  = (const float*)d_in[11];
    const float* g1  = (const float*)d_in[12];
    const float* be1 = (const float*)d_in[13];
    const float* g2  = (const float*)d_in[14];
    const float* be2 = (const float*)d_in[15];
    float* out = (float*)d_out;
    u16* ws = (u16*)d_ws;

    const long SZ = (long)BATCH * NTOK * D_MODEL;  // 3,145,728

    u16* WqT  = ws + 0;          // WqT,WkT contiguous => merged Q+K projection (Nd=768)
    u16* WkT  = ws + 147456;
    u16* WvT  = ws + 294912;
    u16* WoT  = ws + 442368;
    u16* W1T  = ws + 589824;
    u16* W2T  = ws + 1179648;
    u16* QKin = ws + 1769472;
    u16* SRCB = ws + 4915200;
    u16* QtH  = ws + 8060928;    // [8][384][1024]; KtH contiguous after (merged store target)
    u16* KtH  = ws + 11206656;
    u16* VtH  = ws + 14352384;
    u16* BT   = ws + 17498112;   // [8][1024][1024], dead after bias3
    u16* ATT  = ws + 17498112;   // aliases BT (written by attention, after bias3)
    u16* Q2H  = ws + 25886720;   // frag-tiled [64 bh][64 tb][1024], 4,194,304 u16
    u16* K2H  = ws + 30081024;   // frag-tiled, 4,194,304 u16
    u16* V2T  = ws + 34275328;   // frag-tiled [64 bh][16 mb][3072], 3,145,728 u16 (end 37,421,056)
    // aliases (lifetimes disjoint):
    float* Of  = (float*)(ws + 8060928);   // pre-LN1 f32 (over QtH+KtH, dead after bias3)
    float* xf  = (float*)(ws + 14352384);  // post-LN1 f32 (over VtH + BT head; ATT dead by then)
    u16*   xbf = QKin;                     // post-LN1 bf16 (QKin dead after projections)
    u16*   hbf = Q2H;                      // FF hidden [8192][1536] (over Q2H..V2T, dead by FF1)
    float* ff  = (float*)(ws + 8060928);   // pre-LN2 f32 (over Of, dead after LN1)

    // 1. adds + casts
    add_cast_kernel<<<(int)(SZ / 4 + 255) / 256, 256, 0, stream>>>(
        (const float4*)src, (const float4*)pos, (ushort4*)QKin, (ushort4*)SRCB, (int)(SZ / 4));
    // 2. weight transposes
    dim3 tb(32, 8);
    castT4_kernel<<<dim3(12, 12, 4), tb, 0, stream>>>(Wq, Wk, Wv, Wo, WqT, WkT, WvT, WoT);
    castT_kernel<<<dim3(48, 12), tb, 0, stream>>>(W1, W1T, 384, 1536);
    castT_kernel<<<dim3(12, 48), tb, 0, stream>>>(W2, W2T, 1536, 384);
    // 3. relative bias (transposed, bf16)
    biasT_bf16_kernel<<<32768, 256, 0, stream>>>(table, BT);
    // 4. projections -> head-major transposed bf16.  Q and K merged (Nd=768).
    mgemm128_kernel<8, false, false, false><<<dim3(6, 64), 256, 0, stream>>>(
        QKin, WqT, nullptr, nullptr, QtH, nullptr, nullptr,
        384, 384, 384, 0, 0);
    mgemm128_kernel<8, false, false, false><<<dim3(3, 64), 256, 0, stream>>>(
        SRCB, WvT, nullptr, nullptr, VtH, nullptr, nullptr,
        384, 384, 384, 0, 0);
    // 5. fused bias matmuls -> fragment-tiled Q2H (scaled), K2H, V2T
    bias3_kernel<<<768, 256, 0, stream>>>(BT, QtH, KtH, VtH, Q2H, K2H, V2T);
    // 6. attention (wave-split KV, XCD-swizzled, coalesced fragment loads)
    attn_mfma_kernel<<<4096, 256, 0, stream>>>(Q2H, K2H, V2T, ATT);
    // 7. o = att @ Wo + bo + src
    mgemm128_kernel<1, true, true, false><<<dim3(3, 64), 256, 0, stream>>>(
        ATT, WoT, Of, nullptr, nullptr, bo, src,
        384, 384, 384, 384, 384);
    // 8. x = LN1(o)
    ln_kernel<<<8192, 128, 0, stream>>>(Of, nullptr, g1, be1, xf, xbf, 0);
    // 9. h = gelu(x @ W1 + b1)
    mgemm128_kernel<2, true, false, true><<<dim3(12, 64), 256, 0, stream>>>(
        xbf, W1T, nullptr, hbf, nullptr, b1, nullptr,
        384, 384, 384, 1536, 0);
    // 10. ff = h @ W2 + b2 + x
    mgemm128_kernel<1, true, true, false><<<dim3(3, 64), 256, 0, stream>>>(
        hbf, W2T, ff, nullptr, nullptr, b2, xf,
        1536, 1536, 1536, 384, 384);
    // 11. out = LN2(ff)
    ln_kernel<<<8192, 128, 0, stream>>>(ff, nullptr, g2, be2, out, nullptr, 0);
}

// Round 16
// 229.026 us; speedup vs baseline: 1.2247x; 1.2247x over previous
//
#include <hip/hip_runtime.h>
#include <math.h>

#define D_MODEL 384
#define HEADS 8
#define DIM_HEAD 48
#define NTOK 1024
#define BATCH 8
#define D_FF 1536
#define LN_EPS 1e-5f

typedef unsigned short u16;
typedef unsigned int u32;
typedef unsigned long long u64;
typedef short short8 __attribute__((ext_vector_type(8)));
typedef float f32x4 __attribute__((ext_vector_type(4)));

union F8 { short8 v; u64 q[2]; u16 u[8]; uint4 u4; };

__device__ __forceinline__ u16 f2bf(float f) {
    union { float f; unsigned u; } c; c.f = f;
    unsigned r = c.u + 0x7FFFu + ((c.u >> 16) & 1u);
    return (u16)(r >> 16);
}
__device__ __forceinline__ float bf2f(u16 u) {
    union { unsigned u; float f; } c; c.u = ((unsigned)u) << 16; return c.f;
}
__device__ __forceinline__ void gload_lds16(const u16* g, u16* l) {
    __builtin_amdgcn_global_load_lds(
        (const __attribute__((address_space(1))) void*)g,
        (__attribute__((address_space(3))) void*)l, 16, 0, 0);
}

// ---------------- add + cast (QKin = bf16(src+pos), SRCB = bf16(src)) ----------------
__global__ __launch_bounds__(256) void add_cast_kernel(
        const float4* __restrict__ a, const float4* __restrict__ b,
        ushort4* __restrict__ o1, ushort4* __restrict__ o2, int n4) {
    int i = blockIdx.x * blockDim.x + threadIdx.x;
    if (i >= n4) return;
    float4 x = a[i], y = b[i];
    ushort4 u1, u2;
    u1.x = f2bf(x.x + y.x); u1.y = f2bf(x.y + y.y); u1.z = f2bf(x.z + y.z); u1.w = f2bf(x.w + y.w);
    u2.x = f2bf(x.x); u2.y = f2bf(x.y); u2.z = f2bf(x.z); u2.w = f2bf(x.w);
    o1[i] = u1; o2[i] = u2;
}

// ---------------- 4x square transpose + cast (384x384), z-batched ----------------
__global__ __launch_bounds__(256) void castT4_kernel(
        const float* __restrict__ i0, const float* __restrict__ i1,
        const float* __restrict__ i2, const float* __restrict__ i3,
        u16* __restrict__ o0, u16* __restrict__ o1,
        u16* __restrict__ o2, u16* __restrict__ o3) {
    const float* in  = (blockIdx.z == 0) ? i0 : (blockIdx.z == 1) ? i1 : (blockIdx.z == 2) ? i2 : i3;
    u16*         out = (blockIdx.z == 0) ? o0 : (blockIdx.z == 1) ? o1 : (blockIdx.z == 2) ? o2 : o3;
    __shared__ float t[32][33];
    int c0 = blockIdx.x * 32, r0 = blockIdx.y * 32;
    int tx = threadIdx.x, ty = threadIdx.y;  // 32 x 8
    for (int i = ty; i < 32; i += 8)
        t[i][tx] = in[(long)(r0 + i) * 384 + c0 + tx];
    __syncthreads();
    for (int i = ty; i < 32; i += 8)
        out[(long)(c0 + i) * 384 + r0 + tx] = f2bf(t[tx][i]);
}

// ---------------- transpose + cast: out[c][r] = bf16(in[r][c]) ----------------
__global__ __launch_bounds__(256) void castT_kernel(
        const float* __restrict__ in, u16* __restrict__ out, int R, int C) {
    __shared__ float t[32][33];
    int c0 = blockIdx.x * 32, r0 = blockIdx.y * 32;
    int tx = threadIdx.x, ty = threadIdx.y;  // 32 x 8
    for (int i = ty; i < 32; i += 8)
        t[i][tx] = in[(long)(r0 + i) * C + c0 + tx];
    __syncthreads();
    for (int i = ty; i < 32; i += 8)
        out[(long)(c0 + i) * R + r0 + tx] = f2bf(t[tx][i]);
}

// ---------------- relative bias, transposed, bf16: BT[h][n][m] = bias[h][m][n] ----------------
__global__ __launch_bounds__(256) void biasT_bf16_kernel(const float* __restrict__ table,
                                                         u16* __restrict__ BT) {
    long i = (long)blockIdx.x * blockDim.x + threadIdx.x;
    const long total = (long)HEADS * NTOK * NTOK;
    if (i >= total) return;
    int m = (int)(i & 1023);
    int n = (int)((i >> 10) & 1023);
    int h = (int)(i >> 20);
    int dy = (m >> 5) - (n >> 5) + 31;
    int dx = (m & 31) - (n & 31) + 31;
    BT[i] = f2bf(table[(dy * 63 + dx) * HEADS + h]);
}

// ---------------- MFMA GEMM, 128x128 tile, double-buffered global_load_lds ----------------
// Counted-vmcnt pipeline with sched_barrier(0) pins: raw s_barrier is NOT a compiler
// memory fence, so every region boundary is pinned to stop DMA-issue hoisting (R14 race).
template<int OUTMODE, bool HAS_BIAS, bool HAS_RES, bool GELU_>
__global__ __launch_bounds__(256) void mgemm128_kernel(
        const u16* __restrict__ Ab, const u16* __restrict__ Btb,
        float* __restrict__ Cf, u16* __restrict__ Cb, u16* __restrict__ Ct,
        const float* __restrict__ bias, const float* __restrict__ Rb,
        int Kd, int lda, int ldbt, int ldc, int ldr) {
    __shared__ u16 As[2][128 * 32];
    __shared__ u16 Bs[2][128 * 32];
    int tid = threadIdx.x, wave = tid >> 6, lane = tid & 63, g = lane >> 4, l15 = lane & 15;
    int wm = wave >> 1, wn = wave & 1;
    int row0 = blockIdx.y * 128, col0 = blockIdx.x * 128;

    f32x4 acc[4][4] = {};

    int sr = lane >> 2, sk = lane & 3;
    const u16* aG0 = Ab  + (long)(row0 + wave * 16 + sr) * lda  + sk * 8;
    const u16* aG1 = Ab  + (long)(row0 + (wave + 4) * 16 + sr) * lda  + sk * 8;
    const u16* bG0 = Btb + (long)(col0 + wave * 16 + sr) * ldbt + sk * 8;
    const u16* bG1 = Btb + (long)(col0 + (wave + 4) * 16 + sr) * ldbt + sk * 8;
    int w0off = (wave * 16) * 32, w1off = ((wave + 4) * 16) * 32;

    const int T = Kd >> 5;
    gload_lds16(aG0, &As[0][w0off]);
    gload_lds16(aG1, &As[0][w1off]);
    gload_lds16(bG0, &Bs[0][w0off]);
    gload_lds16(bG1, &Bs[0][w1off]);
    __builtin_amdgcn_sched_barrier(0);

    for (int t = 0; t < T; ++t) {
        int cur = t & 1, nxt = cur ^ 1;
        if (t + 1 < T) {
            int k1 = (t + 1) << 5;
            gload_lds16(aG0 + k1, &As[nxt][w0off]);
            gload_lds16(aG1 + k1, &As[nxt][w1off]);
            gload_lds16(bG0 + k1, &Bs[nxt][w0off]);
            gload_lds16(bG1 + k1, &Bs[nxt][w1off]);
            __builtin_amdgcn_sched_barrier(0);
            asm volatile("s_waitcnt vmcnt(4)" ::: "memory");  // tile t landed; t+1 in flight
        } else {
            asm volatile("s_waitcnt vmcnt(0)" ::: "memory");
        }
        __builtin_amdgcn_sched_barrier(0);
        __builtin_amdgcn_s_barrier();
        __builtin_amdgcn_sched_barrier(0);
        F8 af[4], bfr[4];
#pragma unroll
        for (int fm = 0; fm < 4; ++fm)
            af[fm].u4 = *(const uint4*)&As[cur][(wm * 64 + fm * 16 + l15) * 32 + g * 8];
#pragma unroll
        for (int fn = 0; fn < 4; ++fn)
            bfr[fn].u4 = *(const uint4*)&Bs[cur][(wn * 64 + fn * 16 + l15) * 32 + g * 8];
#pragma unroll
        for (int fm = 0; fm < 4; ++fm)
#pragma unroll
            for (int fn = 0; fn < 4; ++fn)
                acc[fm][fn] = __builtin_amdgcn_mfma_f32_16x16x32_bf16(
                    af[fm].v, bfr[fn].v, acc[fm][fn], 0, 0, 0);
        __builtin_amdgcn_sched_barrier(0);
        __builtin_amdgcn_s_barrier();   // all waves done reading buf[cur] before re-stage
        __builtin_amdgcn_sched_barrier(0);
    }

#pragma unroll
    for (int fm = 0; fm < 4; ++fm) {
        int rbase = row0 + wm * 64 + fm * 16 + g * 4;
#pragma unroll
        for (int fn = 0; fn < 4; ++fn) {
            int c = col0 + wn * 64 + fn * 16 + l15;
            float bv = HAS_BIAS ? bias[c] : 0.f;
            float vs[4];
#pragma unroll
            for (int r = 0; r < 4; ++r) {
                float v = acc[fm][fn][r] + bv;
                if (HAS_RES) v += Rb[(long)(rbase + r) * ldr + c];
                if (GELU_)   v = 0.5f * v * (1.f + erff(v * 0.70710678118654752f));
                vs[r] = v;
                if (OUTMODE & 1) Cf[(long)(rbase + r) * ldc + c] = v;
                if (OUTMODE & 2) Cb[(long)(rbase + r) * ldc + c] = f2bf(v);
            }
            if (OUTMODE & 8) {
                int hh2 = (c * 683) >> 15; int dd = c - hh2 * 48;   // valid for c < 768
                int bb2 = rbase >> 10;     int mm = rbase & 1023;
                ushort4 o;
                o.x = f2bf(vs[0]); o.y = f2bf(vs[1]); o.z = f2bf(vs[2]); o.w = f2bf(vs[3]);
                *(ushort4*)&Ct[(long)hh2 * 393216 + (long)(bb2 * 48 + dd) * 1024 + mm] = o;
            }
        }
    }
}

// ---------------- fused bias matmuls -> MFMA-fragment-tiled Q/K/V ----------------
// 1D grid 768, XCD-swizzled (one head per XCD). Double-buffered staging, pinned regions.
__global__ __launch_bounds__(256) void bias3_kernel(
        const u16* __restrict__ BT, const u16* __restrict__ QtH,
        const u16* __restrict__ KtH, const u16* __restrict__ VtH,
        u16* __restrict__ Q2H, u16* __restrict__ K2H, u16* __restrict__ V2T) {
    int bid = blockIdx.x;
    int widx = (bid & 7) * 96 + (bid >> 3);   // bijective (768 % 8 == 0)
    int h = widx / 96;
    int rem = widx - h * 96;
    int ry = rem / 6, cx = rem - ry * 6;
    const long hb = (long)h * 393216;
    const u16* A = BT + (long)h * 1048576;
    __shared__ u16 As[2][64 * 32];
    __shared__ u16 Bq[2][64 * 32], Bk[2][64 * 32], Bv[2][64 * 32];
    int tid = threadIdx.x, wave = tid >> 6, lane = tid & 63, g = lane >> 4, l15 = lane & 15;
    int wm = wave >> 1, wn = wave & 1;
    int row0 = ry * 64, col0 = cx * 64;
    f32x4 acc[3][2][2] = {};

    int sr = lane >> 2, sk = lane & 3;
    const u16* aG = A   + (long)(row0 + wave * 16 + sr) * 1024 + sk * 8;
    const u16* qG = QtH + hb + (long)(col0 + wave * 16 + sr) * 1024 + sk * 8;
    const u16* kG = KtH + hb + (long)(col0 + wave * 16 + sr) * 1024 + sk * 8;
    const u16* vG = VtH + hb + (long)(col0 + wave * 16 + sr) * 1024 + sk * 8;
    int woff = (wave * 16) * 32;

    gload_lds16(aG, &As[0][woff]);
    gload_lds16(qG, &Bq[0][woff]);
    gload_lds16(kG, &Bk[0][woff]);
    gload_lds16(vG, &Bv[0][woff]);
    __builtin_amdgcn_sched_barrier(0);

    for (int t = 0; t < 32; ++t) {
        int cur = t & 1, nxt = cur ^ 1;
        if (t + 1 < 32) {
            int k1 = (t + 1) << 5;
            gload_lds16(aG + k1, &As[nxt][woff]);
            gload_lds16(qG + k1, &Bq[nxt][woff]);
            gload_lds16(kG + k1, &Bk[nxt][woff]);
            gload_lds16(vG + k1, &Bv[nxt][woff]);
            __builtin_amdgcn_sched_barrier(0);
            asm volatile("s_waitcnt vmcnt(4)" ::: "memory");
        } else {
            asm volatile("s_waitcnt vmcnt(0)" ::: "memory");
        }
        __builtin_amdgcn_sched_barrier(0);
        __builtin_amdgcn_s_barrier();
        __builtin_amdgcn_sched_barrier(0);
        F8 af0, af1, b0, b1;
        af0.u4 = *(const uint4*)&As[cur][(wm * 32 + l15) * 32 + g * 8];
        af1.u4 = *(const uint4*)&As[cur][(wm * 32 + 16 + l15) * 32 + g * 8];
        // Q
        b0.u4 = *(const uint4*)&Bq[cur][(wn * 32 + l15) * 32 + g * 8];
        b1.u4 = *(const uint4*)&Bq[cur][(wn * 32 + 16 + l15) * 32 + g * 8];
        acc[0][0][0] = __builtin_amdgcn_mfma_f32_16x16x32_bf16(af0.v, b0.v, acc[0][0][0], 0, 0, 0);
        acc[0][0][1] = __builtin_amdgcn_mfma_f32_16x16x32_bf16(af0.v, b1.v, acc[0][0][1], 0, 0, 0);
        acc[0][1][0] = __builtin_amdgcn_mfma_f32_16x16x32_bf16(af1.v, b0.v, acc[0][1][0], 0, 0, 0);
        acc[0][1][1] = __builtin_amdgcn_mfma_f32_16x16x32_bf16(af1.v, b1.v, acc[0][1][1], 0, 0, 0);
        // K
        b0.u4 = *(const uint4*)&Bk[cur][(wn * 32 + l15) * 32 + g * 8];
        b1.u4 = *(const uint4*)&Bk[cur][(wn * 32 + 16 + l15) * 32 + g * 8];
        acc[1][0][0] = __builtin_amdgcn_mfma_f32_16x16x32_bf16(af0.v, b0.v, acc[1][0][0], 0, 0, 0);
        acc[1][0][1] = __builtin_amdgcn_mfma_f32_16x16x32_bf16(af0.v, b1.v, acc[1][0][1], 0, 0, 0);
        acc[1][1][0] = __builtin_amdgcn_mfma_f32_16x16x32_bf16(af1.v, b0.v, acc[1][1][0], 0, 0, 0);
        acc[1][1][1] = __builtin_amdgcn_mfma_f32_16x16x32_bf16(af1.v, b1.v, acc[1][1][1], 0, 0, 0);
        // V
        b0.u4 = *(const uint4*)&Bv[cur][(wn * 32 + l15) * 32 + g * 8];
        b1.u4 = *(const uint4*)&Bv[cur][(wn * 32 + 16 + l15) * 32 + g * 8];
        acc[2][0][0] = __builtin_amdgcn_mfma_f32_16x16x32_bf16(af0.v, b0.v, acc[2][0][0], 0, 0, 0);
        acc[2][0][1] = __builtin_amdgcn_mfma_f32_16x16x32_bf16(af0.v, b1.v, acc[2][0][1], 0, 0, 0);
        acc[2][1][0] = __builtin_amdgcn_mfma_f32_16x16x32_bf16(af1.v, b0.v, acc[2][1][0], 0, 0, 0);
        acc[2][1][1] = __builtin_amdgcn_mfma_f32_16x16x32_bf16(af1.v, b1.v, acc[2][1][1], 0, 0, 0);
        __builtin_amdgcn_sched_barrier(0);
        __builtin_amdgcn_s_barrier();
        __builtin_amdgcn_sched_barrier(0);
    }

    // Q pre-scale: 48^-0.5 * log2(e)  (attention softmax runs in exp2 domain)
    const float qsc = 0.14433756729740643f * 1.4426950408889634f;
#pragma unroll
    for (int fm = 0; fm < 2; ++fm) {
        int rbase = row0 + wm * 32 + fm * 16 + g * 4;  // token (n for Q/K, m for V)
#pragma unroll
        for (int fn = 0; fn < 2; ++fn) {
            int c = col0 + wn * 32 + fn * 16 + l15;    // 0..383 = b*48+d
            int b2 = (c * 683) >> 15, d = c - b2 * 48;
            long bh = (long)h * 8 + b2;
            ushort4 rq = *(const ushort4*)&QtH[hb + (long)c * 1024 + rbase];
            ushort4 rk = *(const ushort4*)&KtH[hb + (long)c * 1024 + rbase];
            ushort4 rv = *(const ushort4*)&VtH[hb + (long)c * 1024 + rbase];
            const u16* rqa = (const u16*)&rq;
            const u16* rka = (const u16*)&rk;
            const u16* rva = (const u16*)&rv;
            int ks = d >> 5, g3 = (d >> 3) & 3, e = d & 7;
            long qbase = ((bh * 64 + (rbase >> 4)) * 8 + ks * 4 + g3) * 128
                       + (rbase & 15) * 8 + e;
            ushort4 vo;
            u16* voa = (u16*)&vo;
#pragma unroll
            for (int r = 0; r < 4; ++r) {
                float qv = acc[0][fm][fn][r] + bf2f(rqa[r]);
                Q2H[qbase + r * 8] = f2bf(qv * qsc);
                float kv = acc[1][fm][fn][r] + bf2f(rka[r]);
                K2H[qbase + r * 8] = f2bf(kv);
                voa[r] = f2bf(acc[2][fm][fn][r] + bf2f(rva[r]));
            }
            long vaddr = ((((bh * 16 + (rbase >> 6)) * 3 + (d >> 4)) * 2
                          + ((rbase >> 5) & 1)) * 4 + ((rbase >> 3) & 3)) * 128
                       + (d & 15) * 8 + (rbase & 7);
            *(ushort4*)&V2T[vaddr] = vo;
            if (d < 16) {
                long pbase = ((bh * 64 + (rbase >> 4)) * 8 + 4 + 2 + (d >> 3)) * 128
                           + (rbase & 15) * 8 + (d & 7);
#pragma unroll
                for (int r = 0; r < 4; ++r) {
                    Q2H[pbase + r * 8] = 0;
                    K2H[pbase + r * 8] = 0;
                }
            }
        }
    }
}

// ---------------- flash attention, MFMA, bf16, wave-split KV, fragment-tiled ----------------
// 1D grid 4096 XCD-swizzled. (256,4): VGPR 64, no spill — the (256,8) attempt spilled to scratch.
__global__ __launch_bounds__(256, 4) void attn_mfma_kernel(
        const u16* __restrict__ Q2H, const u16* __restrict__ K2H,
        const u16* __restrict__ V2T, u16* __restrict__ O) {
    int bid = blockIdx.x;
    int widx = (bid & 7) * 512 + (bid >> 3);   // bijective (4096 % 8 == 0)
    int qb = widx & 63;
    int h  = (widx >> 6) & 7;
    int b  = widx >> 9;
    int tid = threadIdx.x, wave = tid >> 6, lane = tid & 63, g = lane >> 4, l15 = lane & 15;

    __shared__ char smem[13824];
    u16   (*Pl)[16][72]  = (u16(*)[16][72])smem;            // [4][16][72] u16 = 9216 B
    float (*Oc)[16][52]  = (float(*)[16][52])smem;          // [4][16][52] f32 = 13312 B
    float (*MLc)[16][2]  = (float(*)[16][2])(smem + 13312); // 512 B
    const int sw = ((l15 >> 3) & 1) << 5;
    const int loff = (g * 16 + l15) * 8;   // fragment lane offset (u16)

    const long bh = (long)(h * 8 + b);
    const u16* qtile = Q2H + (bh * 64 + qb) * 1024;
    F8 qf0, qf1;
    qf0.u4 = *(const uint4*)(qtile + loff);
    qf1.u4 = *(const uint4*)(qtile + 512 + loff);

    f32x4 oacc[3] = {};
    float runm = -1e30f, runl = 0.f;

#pragma unroll
    for (int it = 0; it < 4; ++it) {
        // ---- QK^T for this wave's 64 keys (4 key-tiles of 16) ----
        f32x4 s[4] = {};
#pragma unroll
        for (int mt = 0; mt < 4; ++mt) {
            const u16* ktile = K2H + (bh * 64 + wave * 16 + it * 4 + mt) * 1024;
            F8 kf0, kf1;
            kf0.u4 = *(const uint4*)(ktile + loff);
            kf1.u4 = *(const uint4*)(ktile + 512 + loff);
            s[mt] = __builtin_amdgcn_mfma_f32_16x16x32_bf16(kf0.v, qf0.v, s[mt], 0, 0, 0);
            s[mt] = __builtin_amdgcn_mfma_f32_16x16x32_bf16(kf1.v, qf1.v, s[mt], 0, 0, 0);
        }

        // ---- V fragments (independent; latency hides under softmax) ----
        const u16* vtile = V2T + (bh * 16 + wave * 4 + it) * 3072;
        F8 vf[3][2];
#pragma unroll
        for (int dt = 0; dt < 3; ++dt)
#pragma unroll
            for (int ks = 0; ks < 2; ++ks)
                vf[dt][ks].u4 = *(const uint4*)(vtile + (dt * 2 + ks) * 512 + loff);

        // ---- online softmax (exp2 domain; scale*log2e pre-folded into Q) ----
        float p[16];
#pragma unroll
        for (int i = 0; i < 16; ++i) p[i] = s[i >> 2][i & 3];
        float pm[8];
#pragma unroll
        for (int i = 0; i < 8; ++i) pm[i] = fmaxf(p[i], p[i + 8]);
#pragma unroll
        for (int st = 4; st > 0; st >>= 1)
#pragma unroll
            for (int i = 0; i < st; ++i) pm[i] = fmaxf(pm[i], pm[i + st]);
        float tmax = pm[0];
        tmax = fmaxf(tmax, __shfl_xor(tmax, 16));
        tmax = fmaxf(tmax, __shfl_xor(tmax, 32));
        if (!__all(tmax <= runm + 8.0f)) {     // defer-max (T13)
            float nm = fmaxf(runm, tmax);
            float corr = __builtin_amdgcn_exp2f(runm - nm);
            runm = nm; runl *= corr;
#pragma unroll
            for (int dt = 0; dt < 3; ++dt) {
                oacc[dt][0] *= corr; oacc[dt][1] *= corr;
                oacc[dt][2] *= corr; oacc[dt][3] *= corr;
            }
        }
        float ps = 0.f;
#pragma unroll
        for (int i = 0; i < 16; ++i) { p[i] = __builtin_amdgcn_exp2f(p[i] - runm); ps += p[i]; }
        ps += __shfl_xor(ps, 16);
        ps += __shfl_xor(ps, 32);
        runl += ps;

        // ---- P -> bf16 -> per-wave LDS redistribution ----
#pragma unroll
        for (int mt = 0; mt < 4; ++mt) {
            u32 wa, wb;
            asm("v_cvt_pk_bf16_f32 %0, %1, %2" : "=v"(wa) : "v"(p[mt * 4]), "v"(p[mt * 4 + 1]));
            asm("v_cvt_pk_bf16_f32 %0, %1, %2" : "=v"(wb) : "v"(p[mt * 4 + 2]), "v"(p[mt * 4 + 3]));
            *(u64*)&Pl[wave][l15][(mt * 16 + g * 4) ^ sw] = ((u64)wb << 32) | wa;
        }
        F8 pb[2];
#pragma unroll
        for (int ks = 0; ks < 2; ++ks) {
            pb[ks].q[0] = *(const u64*)&Pl[wave][l15][(ks * 32 + g * 8) ^ sw];
            pb[ks].q[1] = *(const u64*)&Pl[wave][l15][((ks * 32 + g * 8) + 4) ^ sw];
        }

        // ---- PV ----
#pragma unroll
        for (int dt = 0; dt < 3; ++dt) {
            oacc[dt] = __builtin_amdgcn_mfma_f32_16x16x32_bf16(vf[dt][0].v, pb[0].v, oacc[dt], 0, 0, 0);
            oacc[dt] = __builtin_amdgcn_mfma_f32_16x16x32_bf16(vf[dt][1].v, pb[1].v, oacc[dt], 0, 0, 0);
        }
    }

    // ---- cross-wave combine ----
    __syncthreads();   // all waves done with Pl (unioned with Oc)
#pragma unroll
    for (int dt = 0; dt < 3; ++dt)
#pragma unroll
        for (int r = 0; r < 4; ++r)
            Oc[wave][l15][dt * 16 + g * 4 + r] = oacc[dt][r];
    if (g == 0) { MLc[wave][l15][0] = runm; MLc[wave][l15][1] = runl; }
    __syncthreads();

    if (wave == 0) {
        float mm[4], cc[4];
#pragma unroll
        for (int w = 0; w < 4; ++w) mm[w] = MLc[w][l15][0];
        float M = fmaxf(fmaxf(mm[0], mm[1]), fmaxf(mm[2], mm[3]));
        float LL = 0.f;
#pragma unroll
        for (int w = 0; w < 4; ++w) {
            cc[w] = __builtin_amdgcn_exp2f(mm[w] - M);
            LL += cc[w] * MLc[w][l15][1];
        }
        float inv = 1.f / LL;
        u16* op = O + ((long)b * NTOK + qb * 16 + l15) * D_MODEL + h * DIM_HEAD;
#pragma unroll
        for (int dt = 0; dt < 3; ++dt) {
            ushort4 o;
#pragma unroll
            for (int r = 0; r < 4; ++r) {
                int d = dt * 16 + g * 4 + r;
                float v = cc[0] * Oc[0][l15][d] + cc[1] * Oc[1][l15][d]
                        + cc[2] * Oc[2][l15][d] + cc[3] * Oc[3][l15][d];
                ((u16*)&o)[r] = f2bf(v * inv);
            }
            *(ushort4*)(op + dt * 16 + g * 4) = o;
        }
    }
}

// ---------------- layernorm (+optional residual, optional bf16 copy) ----------------
__global__ __launch_bounds__(128) void ln_kernel(
        const float* __restrict__ X, const float* __restrict__ Rb,
        const float* __restrict__ g, const float* __restrict__ be,
        float* __restrict__ O, u16* __restrict__ Obf, int hasRes) {
    int row = blockIdx.x;
    int tid = threadIdx.x;
    const float* x = X + (long)row * D_MODEL;
    float v[3];
#pragma unroll
    for (int l = 0; l < 3; ++l) {
        int c = tid + l * 128;
        v[l] = x[c];
        if (hasRes) v[l] += Rb[(long)row * D_MODEL + c];
    }
    __shared__ float red[128];
    float s = v[0] + v[1] + v[2];
    red[tid] = s; __syncthreads();
    for (int st = 64; st > 0; st >>= 1) {
        if (tid < st) red[tid] += red[tid + st];
        __syncthreads();
    }
    float mean = red[0] * (1.f / 384.f);
    __syncthreads();
    float sq = 0.f;
#pragma unroll
    for (int l = 0; l < 3; ++l) { float d = v[l] - mean; sq += d * d; }
    red[tid] = sq; __syncthreads();
    for (int st = 64; st > 0; st >>= 1) {
        if (tid < st) red[tid] += red[tid + st];
        __syncthreads();
    }
    float rstd = rsqrtf(red[0] * (1.f / 384.f) + LN_EPS);
#pragma unroll
    for (int l = 0; l < 3; ++l) {
        int c = tid + l * 128;
        float o = (v[l] - mean) * rstd * g[c] + be[c];
        O[(long)row * D_MODEL + c] = o;
        if (Obf) Obf[(long)row * D_MODEL + c] = f2bf(o);
    }
}

extern "C" void kernel_launch(void* const* d_in, const int* in_sizes, int n_in,
                              void* d_out, int out_size, void* d_ws, size_t ws_size,
                              hipStream_t stream) {
    const float* src   = (const float*)d_in[0];
    const float* pos   = (const float*)d_in[1];
    const float* table = (const float*)d_in[2];
    const float* Wq  = (const float*)d_in[3];
    const float* Wk  = (const float*)d_in[4];
    const float* Wv  = (const float*)d_in[5];
    const float* Wo  = (const float*)d_in[6];
    const float* bo  = (const float*)d_in[7];
    const float* W1  = (const float*)d_in[8];
    const float* b1  = (const float*)d_in[9];
    const float* W2  = (const float*)d_in[10];
    const float* b2  = (const float*)d_in[11];
    const float* g1  = (const float*)d_in[12];
    const float* be1 = (const float*)d_in[13];
    const float* g2  = (const float*)d_in[14];
    const float* be2 = (const float*)d_in[15];
    float* out = (float*)d_out;
    u16* ws = (u16*)d_ws;

    const long SZ = (long)BATCH * NTOK * D_MODEL;  // 3,145,728

    u16* WqT  = ws + 0;          // WqT,WkT contiguous => merged Q+K projection (Nd=768)
    u16* WkT  = ws + 147456;
    u16* WvT  = ws + 294912;
    u16* WoT  = ws + 442368;
    u16* W1T  = ws + 589824;
    u16* W2T  = ws + 1179648;
    u16* QKin = ws + 1769472;
    u16* SRCB = ws + 4915200;
    u16* QtH  = ws + 8060928;    // [8][384][1024]; KtH contiguous after (merged store target)
    u16* KtH  = ws + 11206656;
    u16* VtH  = ws + 14352384;
    u16* BT   = ws + 17498112;   // [8][1024][1024], dead after bias3
    u16* ATT  = ws + 17498112;   // aliases BT (written by attention, after bias3)
    u16* Q2H  = ws + 25886720;   // frag-tiled [64 bh][64 tb][1024], 4,194,304 u16
    u16* K2H  = ws + 30081024;   // frag-tiled, 4,194,304 u16
    u16* V2T  = ws + 34275328;   // frag-tiled [64 bh][16 mb][3072], 3,145,728 u16 (end 37,421,056)
    // aliases (lifetimes disjoint):
    float* Of  = (float*)(ws + 8060928);   // pre-LN1 f32 (over QtH+KtH, dead after bias3)
    float* xf  = (float*)(ws + 14352384);  // post-LN1 f32 (over VtH + BT head; ATT dead by then)
    u16*   xbf = QKin;                     // post-LN1 bf16 (QKin dead after projections)
    u16*   hbf = Q2H;                      // FF hidden [8192][1536] (over Q2H..V2T, dead by FF1)
    float* ff  = (float*)(ws + 8060928);   // pre-LN2 f32 (over Of, dead after LN1)

    // 1. adds + casts
    add_cast_kernel<<<(int)(SZ / 4 + 255) / 256, 256, 0, stream>>>(
        (const float4*)src, (const float4*)pos, (ushort4*)QKin, (ushort4*)SRCB, (int)(SZ / 4));
    // 2. weight transposes
    dim3 tb(32, 8);
    castT4_kernel<<<dim3(12, 12, 4), tb, 0, stream>>>(Wq, Wk, Wv, Wo, WqT, WkT, WvT, WoT);
    castT_kernel<<<dim3(48, 12), tb, 0, stream>>>(W1, W1T, 384, 1536);
    castT_kernel<<<dim3(12, 48), tb, 0, stream>>>(W2, W2T, 1536, 384);
    // 3. relative bias (transposed, bf16)
    biasT_bf16_kernel<<<32768, 256, 0, stream>>>(table, BT);
    // 4. projections -> head-major transposed bf16.  Q and K merged (Nd=768).
    mgemm128_kernel<8, false, false, false><<<dim3(6, 64), 256, 0, stream>>>(
        QKin, WqT, nullptr, nullptr, QtH, nullptr, nullptr,
        384, 384, 384, 0, 0);
    mgemm128_kernel<8, false, false, false><<<dim3(3, 64), 256, 0, stream>>>(
        SRCB, WvT, nullptr, nullptr, VtH, nullptr, nullptr,
        384, 384, 384, 0, 0);
    // 5. fused bias matmuls -> fragment-tiled Q2H (scaled), K2H, V2T
    bias3_kernel<<<768, 256, 0, stream>>>(BT, QtH, KtH, VtH, Q2H, K2H, V2T);
    // 6. attention (wave-split KV, XCD-swizzled, coalesced fragment loads)
    attn_mfma_kernel<<<4096, 256, 0, stream>>>(Q2H, K2H, V2T, ATT);
    // 7. o = att @ Wo + bo + src
    mgemm128_kernel<1, true, true, false><<<dim3(3, 64), 256, 0, stream>>>(
        ATT, WoT, Of, nullptr, nullptr, bo, src,
        384, 384, 384, 384, 384);
    // 8. x = LN1(o)
    ln_kernel<<<8192, 128, 0, stream>>>(Of, nullptr, g1, be1, xf, xbf, 0);
    // 9. h = gelu(x @ W1 + b1)
    mgemm128_kernel<2, true, false, true><<<dim3(12, 64), 256, 0, stream>>>(
        xbf, W1T, nullptr, hbf, nullptr, b1, nullptr,
        384, 384, 384, 1536, 0);
    // 10. ff = h @ W2 + b2 + x
    mgemm128_kernel<1, true, true, false><<<dim3(3, 64), 256, 0, stream>>>(
        hbf, W2T, ff, nullptr, nullptr, b2, xf,
        1536, 1536, 1536, 384, 384);
    // 11. out = LN2(ff)
    ln_kernel<<<8192, 128, 0, stream>>>(ff, nullptr, g2, be2, out, nullptr, 0);
}

// Round 17
// 227.395 us; speedup vs baseline: 1.2335x; 1.0072x over previous
//
#include <hip/hip_runtime.h>
#include <math.h>

#define D_MODEL 384
#define HEADS 8
#define DIM_HEAD 48
#define NTOK 1024
#define BATCH 8
#define D_FF 1536
#define LN_EPS 1e-5f

typedef unsigned short u16;
typedef unsigned int u32;
typedef unsigned long long u64;
typedef short short8 __attribute__((ext_vector_type(8)));
typedef float f32x4 __attribute__((ext_vector_type(4)));

union F8 { short8 v; u64 q[2]; u16 u[8]; uint4 u4; };

__device__ __forceinline__ u16 f2bf(float f) {
    union { float f; unsigned u; } c; c.f = f;
    unsigned r = c.u + 0x7FFFu + ((c.u >> 16) & 1u);
    return (u16)(r >> 16);
}
__device__ __forceinline__ float bf2f(u16 u) {
    union { unsigned u; float f; } c; c.u = ((unsigned)u) << 16; return c.f;
}
__device__ __forceinline__ void gload_lds16(const u16* g, u16* l) {
    __builtin_amdgcn_global_load_lds(
        (const __attribute__((address_space(1))) void*)g,
        (__attribute__((address_space(3))) void*)l, 16, 0, 0);
}

// ---------------- add + cast (QKin = bf16(src+pos), SRCB = bf16(src)) ----------------
__global__ __launch_bounds__(256) void add_cast_kernel(
        const float4* __restrict__ a, const float4* __restrict__ b,
        ushort4* __restrict__ o1, ushort4* __restrict__ o2, int n4) {
    int i = blockIdx.x * blockDim.x + threadIdx.x;
    if (i >= n4) return;
    float4 x = a[i], y = b[i];
    ushort4 u1, u2;
    u1.x = f2bf(x.x + y.x); u1.y = f2bf(x.y + y.y); u1.z = f2bf(x.z + y.z); u1.w = f2bf(x.w + y.w);
    u2.x = f2bf(x.x); u2.y = f2bf(x.y); u2.z = f2bf(x.z); u2.w = f2bf(x.w);
    o1[i] = u1; o2[i] = u2;
}

// ---------------- 4x square transpose + cast (384x384), z-batched ----------------
__global__ __launch_bounds__(256) void castT4_kernel(
        const float* __restrict__ i0, const float* __restrict__ i1,
        const float* __restrict__ i2, const float* __restrict__ i3,
        u16* __restrict__ o0, u16* __restrict__ o1,
        u16* __restrict__ o2, u16* __restrict__ o3) {
    const float* in  = (blockIdx.z == 0) ? i0 : (blockIdx.z == 1) ? i1 : (blockIdx.z == 2) ? i2 : i3;
    u16*         out = (blockIdx.z == 0) ? o0 : (blockIdx.z == 1) ? o1 : (blockIdx.z == 2) ? o2 : o3;
    __shared__ float t[32][33];
    int c0 = blockIdx.x * 32, r0 = blockIdx.y * 32;
    int tx = threadIdx.x, ty = threadIdx.y;  // 32 x 8
    for (int i = ty; i < 32; i += 8)
        t[i][tx] = in[(long)(r0 + i) * 384 + c0 + tx];
    __syncthreads();
    for (int i = ty; i < 32; i += 8)
        out[(long)(c0 + i) * 384 + r0 + tx] = f2bf(t[tx][i]);
}

// ---------------- transpose + cast: out[c][r] = bf16(in[r][c]) ----------------
__global__ __launch_bounds__(256) void castT_kernel(
        const float* __restrict__ in, u16* __restrict__ out, int R, int C) {
    __shared__ float t[32][33];
    int c0 = blockIdx.x * 32, r0 = blockIdx.y * 32;
    int tx = threadIdx.x, ty = threadIdx.y;  // 32 x 8
    for (int i = ty; i < 32; i += 8)
        t[i][tx] = in[(long)(r0 + i) * C + c0 + tx];
    __syncthreads();
    for (int i = ty; i < 32; i += 8)
        out[(long)(c0 + i) * R + r0 + tx] = f2bf(t[tx][i]);
}

// ---------------- relative bias, transposed, bf16: BT[h][n][m] = bias[h][m][n] ----------------
__global__ __launch_bounds__(256) void biasT_bf16_kernel(const float* __restrict__ table,
                                                         u16* __restrict__ BT) {
    long i = (long)blockIdx.x * blockDim.x + threadIdx.x;
    const long total = (long)HEADS * NTOK * NTOK;
    if (i >= total) return;
    int m = (int)(i & 1023);
    int n = (int)((i >> 10) & 1023);
    int h = (int)(i >> 20);
    int dy = (m >> 5) - (n >> 5) + 31;
    int dx = (m & 31) - (n & 31) + 31;
    BT[i] = f2bf(table[(dy * 63 + dx) * HEADS + h]);
}

// ---------------- MFMA GEMM, 128x128 tile, double-buffered global_load_lds ----------------
// Counted-vmcnt pipeline with sched_barrier(0) pins: raw s_barrier is NOT a compiler
// memory fence, so every region boundary is pinned to stop DMA-issue hoisting (R14 race).
template<int OUTMODE, bool HAS_BIAS, bool HAS_RES, bool GELU_>
__global__ __launch_bounds__(256) void mgemm128_kernel(
        const u16* __restrict__ Ab, const u16* __restrict__ Btb,
        float* __restrict__ Cf, u16* __restrict__ Cb, u16* __restrict__ Ct,
        const float* __restrict__ bias, const float* __restrict__ Rb,
        int Kd, int lda, int ldbt, int ldc, int ldr) {
    __shared__ u16 As[2][128 * 32];
    __shared__ u16 Bs[2][128 * 32];
    int tid = threadIdx.x, wave = tid >> 6, lane = tid & 63, g = lane >> 4, l15 = lane & 15;
    int wm = wave >> 1, wn = wave & 1;
    int row0 = blockIdx.y * 128, col0 = blockIdx.x * 128;

    f32x4 acc[4][4] = {};

    int sr = lane >> 2, sk = lane & 3;
    const u16* aG0 = Ab  + (long)(row0 + wave * 16 + sr) * lda  + sk * 8;
    const u16* aG1 = Ab  + (long)(row0 + (wave + 4) * 16 + sr) * lda  + sk * 8;
    const u16* bG0 = Btb + (long)(col0 + wave * 16 + sr) * ldbt + sk * 8;
    const u16* bG1 = Btb + (long)(col0 + (wave + 4) * 16 + sr) * ldbt + sk * 8;
    int w0off = (wave * 16) * 32, w1off = ((wave + 4) * 16) * 32;

    const int T = Kd >> 5;
    gload_lds16(aG0, &As[0][w0off]);
    gload_lds16(aG1, &As[0][w1off]);
    gload_lds16(bG0, &Bs[0][w0off]);
    gload_lds16(bG1, &Bs[0][w1off]);
    __builtin_amdgcn_sched_barrier(0);

    for (int t = 0; t < T; ++t) {
        int cur = t & 1, nxt = cur ^ 1;
        if (t + 1 < T) {
            int k1 = (t + 1) << 5;
            gload_lds16(aG0 + k1, &As[nxt][w0off]);
            gload_lds16(aG1 + k1, &As[nxt][w1off]);
            gload_lds16(bG0 + k1, &Bs[nxt][w0off]);
            gload_lds16(bG1 + k1, &Bs[nxt][w1off]);
            __builtin_amdgcn_sched_barrier(0);
            asm volatile("s_waitcnt vmcnt(4)" ::: "memory");  // tile t landed; t+1 in flight
        } else {
            asm volatile("s_waitcnt vmcnt(0)" ::: "memory");
        }
        __builtin_amdgcn_sched_barrier(0);
        __builtin_amdgcn_s_barrier();
        __builtin_amdgcn_sched_barrier(0);
        F8 af[4], bfr[4];
#pragma unroll
        for (int fm = 0; fm < 4; ++fm)
            af[fm].u4 = *(const uint4*)&As[cur][(wm * 64 + fm * 16 + l15) * 32 + g * 8];
#pragma unroll
        for (int fn = 0; fn < 4; ++fn)
            bfr[fn].u4 = *(const uint4*)&Bs[cur][(wn * 64 + fn * 16 + l15) * 32 + g * 8];
#pragma unroll
        for (int fm = 0; fm < 4; ++fm)
#pragma unroll
            for (int fn = 0; fn < 4; ++fn)
                acc[fm][fn] = __builtin_amdgcn_mfma_f32_16x16x32_bf16(
                    af[fm].v, bfr[fn].v, acc[fm][fn], 0, 0, 0);
        __builtin_amdgcn_sched_barrier(0);
        __builtin_amdgcn_s_barrier();   // all waves done reading buf[cur] before re-stage
        __builtin_amdgcn_sched_barrier(0);
    }

#pragma unroll
    for (int fm = 0; fm < 4; ++fm) {
        int rbase = row0 + wm * 64 + fm * 16 + g * 4;
#pragma unroll
        for (int fn = 0; fn < 4; ++fn) {
            int c = col0 + wn * 64 + fn * 16 + l15;
            float bv = HAS_BIAS ? bias[c] : 0.f;
            float vs[4];
#pragma unroll
            for (int r = 0; r < 4; ++r) {
                float v = acc[fm][fn][r] + bv;
                if (HAS_RES) v += Rb[(long)(rbase + r) * ldr + c];
                if (GELU_)   v = 0.5f * v * (1.f + erff(v * 0.70710678118654752f));
                vs[r] = v;
                if (OUTMODE & 1) Cf[(long)(rbase + r) * ldc + c] = v;
                if (OUTMODE & 2) Cb[(long)(rbase + r) * ldc + c] = f2bf(v);
            }
            if (OUTMODE & 8) {
                int hh2 = (c * 683) >> 15; int dd = c - hh2 * 48;   // valid for c < 768
                int bb2 = rbase >> 10;     int mm = rbase & 1023;
                ushort4 o;
                o.x = f2bf(vs[0]); o.y = f2bf(vs[1]); o.z = f2bf(vs[2]); o.w = f2bf(vs[3]);
                *(ushort4*)&Ct[(long)hh2 * 393216 + (long)(bb2 * 48 + dd) * 1024 + mm] = o;
            }
        }
    }
}

// ---------------- fused bias matmuls -> MFMA-fragment-tiled Q/K/V ----------------
// 1D grid 768, XCD-swizzled (one head per XCD). Double-buffered staging, pinned regions.
__global__ __launch_bounds__(256) void bias3_kernel(
        const u16* __restrict__ BT, const u16* __restrict__ QtH,
        const u16* __restrict__ KtH, const u16* __restrict__ VtH,
        u16* __restrict__ Q2H, u16* __restrict__ K2H, u16* __restrict__ V2T) {
    int bid = blockIdx.x;
    int widx = (bid & 7) * 96 + (bid >> 3);   // bijective (768 % 8 == 0)
    int h = widx / 96;
    int rem = widx - h * 96;
    int ry = rem / 6, cx = rem - ry * 6;
    const long hb = (long)h * 393216;
    const u16* A = BT + (long)h * 1048576;
    __shared__ u16 As[2][64 * 32];
    __shared__ u16 Bq[2][64 * 32], Bk[2][64 * 32], Bv[2][64 * 32];
    int tid = threadIdx.x, wave = tid >> 6, lane = tid & 63, g = lane >> 4, l15 = lane & 15;
    int wm = wave >> 1, wn = wave & 1;
    int row0 = ry * 64, col0 = cx * 64;
    f32x4 acc[3][2][2] = {};

    int sr = lane >> 2, sk = lane & 3;
    const u16* aG = A   + (long)(row0 + wave * 16 + sr) * 1024 + sk * 8;
    const u16* qG = QtH + hb + (long)(col0 + wave * 16 + sr) * 1024 + sk * 8;
    const u16* kG = KtH + hb + (long)(col0 + wave * 16 + sr) * 1024 + sk * 8;
    const u16* vG = VtH + hb + (long)(col0 + wave * 16 + sr) * 1024 + sk * 8;
    int woff = (wave * 16) * 32;

    gload_lds16(aG, &As[0][woff]);
    gload_lds16(qG, &Bq[0][woff]);
    gload_lds16(kG, &Bk[0][woff]);
    gload_lds16(vG, &Bv[0][woff]);
    __builtin_amdgcn_sched_barrier(0);

    for (int t = 0; t < 32; ++t) {
        int cur = t & 1, nxt = cur ^ 1;
        if (t + 1 < 32) {
            int k1 = (t + 1) << 5;
            gload_lds16(aG + k1, &As[nxt][woff]);
            gload_lds16(qG + k1, &Bq[nxt][woff]);
            gload_lds16(kG + k1, &Bk[nxt][woff]);
            gload_lds16(vG + k1, &Bv[nxt][woff]);
            __builtin_amdgcn_sched_barrier(0);
            asm volatile("s_waitcnt vmcnt(4)" ::: "memory");
        } else {
            asm volatile("s_waitcnt vmcnt(0)" ::: "memory");
        }
        __builtin_amdgcn_sched_barrier(0);
        __builtin_amdgcn_s_barrier();
        __builtin_amdgcn_sched_barrier(0);
        F8 af0, af1, b0, b1;
        af0.u4 = *(const uint4*)&As[cur][(wm * 32 + l15) * 32 + g * 8];
        af1.u4 = *(const uint4*)&As[cur][(wm * 32 + 16 + l15) * 32 + g * 8];
        // Q
        b0.u4 = *(const uint4*)&Bq[cur][(wn * 32 + l15) * 32 + g * 8];
        b1.u4 = *(const uint4*)&Bq[cur][(wn * 32 + 16 + l15) * 32 + g * 8];
        acc[0][0][0] = __builtin_amdgcn_mfma_f32_16x16x32_bf16(af0.v, b0.v, acc[0][0][0], 0, 0, 0);
        acc[0][0][1] = __builtin_amdgcn_mfma_f32_16x16x32_bf16(af0.v, b1.v, acc[0][0][1], 0, 0, 0);
        acc[0][1][0] = __builtin_amdgcn_mfma_f32_16x16x32_bf16(af1.v, b0.v, acc[0][1][0], 0, 0, 0);
        acc[0][1][1] = __builtin_amdgcn_mfma_f32_16x16x32_bf16(af1.v, b1.v, acc[0][1][1], 0, 0, 0);
        // K
        b0.u4 = *(const uint4*)&Bk[cur][(wn * 32 + l15) * 32 + g * 8];
        b1.u4 = *(const uint4*)&Bk[cur][(wn * 32 + 16 + l15) * 32 + g * 8];
        acc[1][0][0] = __builtin_amdgcn_mfma_f32_16x16x32_bf16(af0.v, b0.v, acc[1][0][0], 0, 0, 0);
        acc[1][0][1] = __builtin_amdgcn_mfma_f32_16x16x32_bf16(af0.v, b1.v, acc[1][0][1], 0, 0, 0);
        acc[1][1][0] = __builtin_amdgcn_mfma_f32_16x16x32_bf16(af1.v, b0.v, acc[1][1][0], 0, 0, 0);
        acc[1][1][1] = __builtin_amdgcn_mfma_f32_16x16x32_bf16(af1.v, b1.v, acc[1][1][1], 0, 0, 0);
        // V
        b0.u4 = *(const uint4*)&Bv[cur][(wn * 32 + l15) * 32 + g * 8];
        b1.u4 = *(const uint4*)&Bv[cur][(wn * 32 + 16 + l15) * 32 + g * 8];
        acc[2][0][0] = __builtin_amdgcn_mfma_f32_16x16x32_bf16(af0.v, b0.v, acc[2][0][0], 0, 0, 0);
        acc[2][0][1] = __builtin_amdgcn_mfma_f32_16x16x32_bf16(af0.v, b1.v, acc[2][0][1], 0, 0, 0);
        acc[2][1][0] = __builtin_amdgcn_mfma_f32_16x16x32_bf16(af1.v, b0.v, acc[2][1][0], 0, 0, 0);
        acc[2][1][1] = __builtin_amdgcn_mfma_f32_16x16x32_bf16(af1.v, b1.v, acc[2][1][1], 0, 0, 0);
        __builtin_amdgcn_sched_barrier(0);
        __builtin_amdgcn_s_barrier();
        __builtin_amdgcn_sched_barrier(0);
    }

    // Q pre-scale: 48^-0.5 * log2(e)  (attention softmax runs in exp2 domain)
    const float qsc = 0.14433756729740643f * 1.4426950408889634f;
#pragma unroll
    for (int fm = 0; fm < 2; ++fm) {
        int rbase = row0 + wm * 32 + fm * 16 + g * 4;  // token (n for Q/K, m for V)
#pragma unroll
        for (int fn = 0; fn < 2; ++fn) {
            int c = col0 + wn * 32 + fn * 16 + l15;    // 0..383 = b*48+d
            int b2 = (c * 683) >> 15, d = c - b2 * 48;
            long bh = (long)h * 8 + b2;
            ushort4 rq = *(const ushort4*)&QtH[hb + (long)c * 1024 + rbase];
            ushort4 rk = *(const ushort4*)&KtH[hb + (long)c * 1024 + rbase];
            ushort4 rv = *(const ushort4*)&VtH[hb + (long)c * 1024 + rbase];
            const u16* rqa = (const u16*)&rq;
            const u16* rka = (const u16*)&rk;
            const u16* rva = (const u16*)&rv;
            int ks = d >> 5, g3 = (d >> 3) & 3, e = d & 7;
            long qbase = ((bh * 64 + (rbase >> 4)) * 8 + ks * 4 + g3) * 128
                       + (rbase & 15) * 8 + e;
            ushort4 vo;
            u16* voa = (u16*)&vo;
#pragma unroll
            for (int r = 0; r < 4; ++r) {
                float qv = acc[0][fm][fn][r] + bf2f(rqa[r]);
                Q2H[qbase + r * 8] = f2bf(qv * qsc);
                float kv = acc[1][fm][fn][r] + bf2f(rka[r]);
                K2H[qbase + r * 8] = f2bf(kv);
                voa[r] = f2bf(acc[2][fm][fn][r] + bf2f(rva[r]));
            }
            long vaddr = ((((bh * 16 + (rbase >> 6)) * 3 + (d >> 4)) * 2
                          + ((rbase >> 5) & 1)) * 4 + ((rbase >> 3) & 3)) * 128
                       + (d & 15) * 8 + (rbase & 7);
            *(ushort4*)&V2T[vaddr] = vo;
            if (d < 16) {
                long pbase = ((bh * 64 + (rbase >> 4)) * 8 + 4 + 2 + (d >> 3)) * 128
                           + (rbase & 15) * 8 + (d & 7);
#pragma unroll
                for (int r = 0; r < 4; ++r) {
                    Q2H[pbase + r * 8] = 0;
                    K2H[pbase + r * 8] = 0;
                }
            }
        }
    }
}

// ---------------- flash attention, MFMA, bf16, wave-split KV, fragment-tiled ----------------
// 1D grid 2048 XCD-swizzled; each block = 32 q-rows (two 16-row q-tiles): K/V fragment
// loads shared by both q-tiles (memory instrs per q-row halved, MFMA:VMEM density 2x).
__global__ __launch_bounds__(256) void attn_mfma_kernel(
        const u16* __restrict__ Q2H, const u16* __restrict__ K2H,
        const u16* __restrict__ V2T, u16* __restrict__ O) {
    int bid = blockIdx.x;
    int widx = (bid & 7) * 256 + (bid >> 3);   // bijective (2048 % 8 == 0)
    int qb = widx & 31;                         // 32-row q-block
    int h  = (widx >> 5) & 7;
    int b  = widx >> 8;
    int tid = threadIdx.x, wave = tid >> 6, lane = tid & 63, g = lane >> 4, l15 = lane & 15;

    __shared__ char smem[13824];
    u16   (*Pl)[16][72]  = (u16(*)[16][72])smem;            // [4][16][72] u16 = 9216 B
    float (*Oc)[16][52]  = (float(*)[16][52])smem;          // [4][16][52] f32 = 13312 B
    float (*MLc)[16][2]  = (float(*)[16][2])(smem + 13312); // 512 B
    const int sw = ((l15 >> 3) & 1) << 5;
    const int loff = (g * 16 + l15) * 8;   // fragment lane offset (u16)

    const long bh = (long)(h * 8 + b);
    const u16* qt = Q2H + (bh * 64 + qb * 2) * 1024;
    F8 qA0, qA1, qB0, qB1;                 // q-tile0 / q-tile1 fragments
    qA0.u4 = *(const uint4*)(qt + loff);
    qA1.u4 = *(const uint4*)(qt + 512 + loff);
    qB0.u4 = *(const uint4*)(qt + 1024 + loff);
    qB1.u4 = *(const uint4*)(qt + 1536 + loff);

    f32x4 oacc0[3] = {}, oacc1[3] = {};
    float runm0 = -1e30f, runl0 = 0.f, runm1 = -1e30f, runl1 = 0.f;

#pragma unroll
    for (int it = 0; it < 4; ++it) {
        // ---- QK^T for this wave's 64 keys, both q-tiles (K frags shared) ----
        f32x4 s0[4] = {}, s1[4] = {};
#pragma unroll
        for (int mt = 0; mt < 4; ++mt) {
            const u16* ktile = K2H + (bh * 64 + wave * 16 + it * 4 + mt) * 1024;
            F8 kf0, kf1;
            kf0.u4 = *(const uint4*)(ktile + loff);
            kf1.u4 = *(const uint4*)(ktile + 512 + loff);
            s0[mt] = __builtin_amdgcn_mfma_f32_16x16x32_bf16(kf0.v, qA0.v, s0[mt], 0, 0, 0);
            s0[mt] = __builtin_amdgcn_mfma_f32_16x16x32_bf16(kf1.v, qA1.v, s0[mt], 0, 0, 0);
            s1[mt] = __builtin_amdgcn_mfma_f32_16x16x32_bf16(kf0.v, qB0.v, s1[mt], 0, 0, 0);
            s1[mt] = __builtin_amdgcn_mfma_f32_16x16x32_bf16(kf1.v, qB1.v, s1[mt], 0, 0, 0);
        }

        // ---- V fragments (shared by both q-tiles) ----
        const u16* vtile = V2T + (bh * 16 + wave * 4 + it) * 3072;
        F8 vf[3][2];
#pragma unroll
        for (int dt = 0; dt < 3; ++dt)
#pragma unroll
            for (int ks = 0; ks < 2; ++ks)
                vf[dt][ks].u4 = *(const uint4*)(vtile + (dt * 2 + ks) * 512 + loff);

        // ---- softmax + PV per q-tile (Pl reused sequentially; same-wave order) ----
#pragma unroll
        for (int qi = 0; qi < 2; ++qi) {
            f32x4* s = qi ? s1 : s0;
            float& runm = qi ? runm1 : runm0;
            float& runl = qi ? runl1 : runl0;
            f32x4* oacc = qi ? oacc1 : oacc0;

            float p[16];
#pragma unroll
            for (int i = 0; i < 16; ++i) p[i] = s[i >> 2][i & 3];
            float pm[8];
#pragma unroll
            for (int i = 0; i < 8; ++i) pm[i] = fmaxf(p[i], p[i + 8]);
#pragma unroll
            for (int st = 4; st > 0; st >>= 1)
#pragma unroll
                for (int i = 0; i < st; ++i) pm[i] = fmaxf(pm[i], pm[i + st]);
            float tmax = pm[0];
            tmax = fmaxf(tmax, __shfl_xor(tmax, 16));
            tmax = fmaxf(tmax, __shfl_xor(tmax, 32));
            if (!__all(tmax <= runm + 8.0f)) {     // defer-max (T13)
                float nm = fmaxf(runm, tmax);
                float corr = __builtin_amdgcn_exp2f(runm - nm);
                runm = nm; runl *= corr;
#pragma unroll
                for (int dt = 0; dt < 3; ++dt) {
                    oacc[dt][0] *= corr; oacc[dt][1] *= corr;
                    oacc[dt][2] *= corr; oacc[dt][3] *= corr;
                }
            }
            float ps = 0.f;
#pragma unroll
            for (int i = 0; i < 16; ++i) { p[i] = __builtin_amdgcn_exp2f(p[i] - runm); ps += p[i]; }
            ps += __shfl_xor(ps, 16);
            ps += __shfl_xor(ps, 32);
            runl += ps;

#pragma unroll
            for (int mt = 0; mt < 4; ++mt) {
                u32 wa, wb;
                asm("v_cvt_pk_bf16_f32 %0, %1, %2" : "=v"(wa) : "v"(p[mt * 4]), "v"(p[mt * 4 + 1]));
                asm("v_cvt_pk_bf16_f32 %0, %1, %2" : "=v"(wb) : "v"(p[mt * 4 + 2]), "v"(p[mt * 4 + 3]));
                *(u64*)&Pl[wave][l15][(mt * 16 + g * 4) ^ sw] = ((u64)wb << 32) | wa;
            }
            F8 pb[2];
#pragma unroll
            for (int ks = 0; ks < 2; ++ks) {
                pb[ks].q[0] = *(const u64*)&Pl[wave][l15][(ks * 32 + g * 8) ^ sw];
                pb[ks].q[1] = *(const u64*)&Pl[wave][l15][((ks * 32 + g * 8) + 4) ^ sw];
            }
#pragma unroll
            for (int dt = 0; dt < 3; ++dt) {
                oacc[dt] = __builtin_amdgcn_mfma_f32_16x16x32_bf16(vf[dt][0].v, pb[0].v, oacc[dt], 0, 0, 0);
                oacc[dt] = __builtin_amdgcn_mfma_f32_16x16x32_bf16(vf[dt][1].v, pb[1].v, oacc[dt], 0, 0, 0);
            }
        }
    }

    // ---- cross-wave combine, q-tile 0 then q-tile 1 ----
#pragma unroll
    for (int qi = 0; qi < 2; ++qi) {
        f32x4* oacc = qi ? oacc1 : oacc0;
        float runm = qi ? runm1 : runm0;
        float runl = qi ? runl1 : runl0;
        __syncthreads();   // Pl/Oc free (loop done; or wave0's previous reads done)
#pragma unroll
        for (int dt = 0; dt < 3; ++dt)
#pragma unroll
            for (int r = 0; r < 4; ++r)
                Oc[wave][l15][dt * 16 + g * 4 + r] = oacc[dt][r];
        if (g == 0) { MLc[wave][l15][0] = runm; MLc[wave][l15][1] = runl; }
        __syncthreads();

        if (wave == 0) {
            float mm[4], cc[4];
#pragma unroll
            for (int w = 0; w < 4; ++w) mm[w] = MLc[w][l15][0];
            float M = fmaxf(fmaxf(mm[0], mm[1]), fmaxf(mm[2], mm[3]));
            float LL = 0.f;
#pragma unroll
            for (int w = 0; w < 4; ++w) {
                cc[w] = __builtin_amdgcn_exp2f(mm[w] - M);
                LL += cc[w] * MLc[w][l15][1];
            }
            float inv = 1.f / LL;
            u16* op = O + ((long)b * NTOK + qb * 32 + qi * 16 + l15) * D_MODEL + h * DIM_HEAD;
#pragma unroll
            for (int dt = 0; dt < 3; ++dt) {
                ushort4 o;
#pragma unroll
                for (int r = 0; r < 4; ++r) {
                    int d = dt * 16 + g * 4 + r;
                    float v = cc[0] * Oc[0][l15][d] + cc[1] * Oc[1][l15][d]
                            + cc[2] * Oc[2][l15][d] + cc[3] * Oc[3][l15][d];
                    ((u16*)&o)[r] = f2bf(v * inv);
                }
                *(ushort4*)(op + dt * 16 + g * 4) = o;
            }
        }
    }
}

// ---------------- layernorm (+optional residual, optional bf16 copy) ----------------
__global__ __launch_bounds__(128) void ln_kernel(
        const float* __restrict__ X, const float* __restrict__ Rb,
        const float* __restrict__ g, const float* __restrict__ be,
        float* __restrict__ O, u16* __restrict__ Obf, int hasRes) {
    int row = blockIdx.x;
    int tid = threadIdx.x;
    const float* x = X + (long)row * D_MODEL;
    float v[3];
#pragma unroll
    for (int l = 0; l < 3; ++l) {
        int c = tid + l * 128;
        v[l] = x[c];
        if (hasRes) v[l] += Rb[(long)row * D_MODEL + c];
    }
    __shared__ float red[128];
    float s = v[0] + v[1] + v[2];
    red[tid] = s; __syncthreads();
    for (int st = 64; st > 0; st >>= 1) {
        if (tid < st) red[tid] += red[tid + st];
        __syncthreads();
    }
    float mean = red[0] * (1.f / 384.f);
    __syncthreads();
    float sq = 0.f;
#pragma unroll
    for (int l = 0; l < 3; ++l) { float d = v[l] - mean; sq += d * d; }
    red[tid] = sq; __syncthreads();
    for (int st = 64; st > 0; st >>= 1) {
        if (tid < st) red[tid] += red[tid + st];
        __syncthreads();
    }
    float rstd = rsqrtf(red[0] * (1.f / 384.f) + LN_EPS);
#pragma unroll
    for (int l = 0; l < 3; ++l) {
        int c = tid + l * 128;
        float o = (v[l] - mean) * rstd * g[c] + be[c];
        O[(long)row * D_MODEL + c] = o;
        if (Obf) Obf[(long)row * D_MODEL + c] = f2bf(o);
    }
}

extern "C" void kernel_launch(void* const* d_in, const int* in_sizes, int n_in,
                              void* d_out, int out_size, void* d_ws, size_t ws_size,
                              hipStream_t stream) {
    const float* src   = (const float*)d_in[0];
    const float* pos   = (const float*)d_in[1];
    const float* table = (const float*)d_in[2];
    const float* Wq  = (const float*)d_in[3];
    const float* Wk  = (const float*)d_in[4];
    const float* Wv  = (const float*)d_in[5];
    const float* Wo  = (const float*)d_in[6];
    const float* bo  = (const float*)d_in[7];
    const float* W1  = (const float*)d_in[8];
    const float* b1  = (const float*)d_in[9];
    const float* W2  = (const float*)d_in[10];
    const float* b2  = (const float*)d_in[11];
    const float* g1  = (const float*)d_in[12];
    const float* be1 = (const float*)d_in[13];
    const float* g2  = (const float*)d_in[14];
    const float* be2 = (const float*)d_in[15];
    float* out = (float*)d_out;
    u16* ws = (u16*)d_ws;

    const long SZ = (long)BATCH * NTOK * D_MODEL;  // 3,145,728

    u16* WqT  = ws + 0;          // WqT,WkT contiguous => merged Q+K projection (Nd=768)
    u16* WkT  = ws + 147456;
    u16* WvT  = ws + 294912;
    u16* WoT  = ws + 442368;
    u16* W1T  = ws + 589824;
    u16* W2T  = ws + 1179648;
    u16* QKin = ws + 1769472;
    u16* SRCB = ws + 4915200;
    u16* QtH  = ws + 8060928;    // [8][384][1024]; KtH contiguous after (merged store target)
    u16* KtH  = ws + 11206656;
    u16* VtH  = ws + 14352384;
    u16* BT   = ws + 17498112;   // [8][1024][1024], dead after bias3
    u16* ATT  = ws + 17498112;   // aliases BT (written by attention, after bias3)
    u16* Q2H  = ws + 25886720;   // frag-tiled [64 bh][64 tb][1024], 4,194,304 u16
    u16* K2H  = ws + 30081024;   // frag-tiled, 4,194,304 u16
    u16* V2T  = ws + 34275328;   // frag-tiled [64 bh][16 mb][3072], 3,145,728 u16 (end 37,421,056)
    // aliases (lifetimes disjoint):
    float* Of  = (float*)(ws + 8060928);   // pre-LN1 f32 (over QtH+KtH, dead after bias3)
    float* xf  = (float*)(ws + 14352384);  // post-LN1 f32 (over VtH + BT head; ATT dead by then)
    u16*   xbf = QKin;                     // post-LN1 bf16 (QKin dead after projections)
    u16*   hbf = Q2H;                      // FF hidden [8192][1536] (over Q2H..V2T, dead by FF1)
    float* ff  = (float*)(ws + 8060928);   // pre-LN2 f32 (over Of, dead after LN1)

    // 1. adds + casts
    add_cast_kernel<<<(int)(SZ / 4 + 255) / 256, 256, 0, stream>>>(
        (const float4*)src, (const float4*)pos, (ushort4*)QKin, (ushort4*)SRCB, (int)(SZ / 4));
    // 2. weight transposes
    dim3 tb(32, 8);
    castT4_kernel<<<dim3(12, 12, 4), tb, 0, stream>>>(Wq, Wk, Wv, Wo, WqT, WkT, WvT, WoT);
    castT_kernel<<<dim3(48, 12), tb, 0, stream>>>(W1, W1T, 384, 1536);
    castT_kernel<<<dim3(12, 48), tb, 0, stream>>>(W2, W2T, 1536, 384);
    // 3. relative bias (transposed, bf16)
    biasT_bf16_kernel<<<32768, 256, 0, stream>>>(table, BT);
    // 4. projections -> head-major transposed bf16.  Q and K merged (Nd=768).
    mgemm128_kernel<8, false, false, false><<<dim3(6, 64), 256, 0, stream>>>(
        QKin, WqT, nullptr, nullptr, QtH, nullptr, nullptr,
        384, 384, 384, 0, 0);
    mgemm128_kernel<8, false, false, false><<<dim3(3, 64), 256, 0, stream>>>(
        SRCB, WvT, nullptr, nullptr, VtH, nullptr, nullptr,
        384, 384, 384, 0, 0);
    // 5. fused bias matmuls -> fragment-tiled Q2H (scaled), K2H, V2T
    bias3_kernel<<<768, 256, 0, stream>>>(BT, QtH, KtH, VtH, Q2H, K2H, V2T);
    // 6. attention (wave-split KV, XCD-swizzled, 32 q-rows/block)
    attn_mfma_kernel<<<2048, 256, 0, stream>>>(Q2H, K2H, V2T, ATT);
    // 7. o = att @ Wo + bo + src
    mgemm128_kernel<1, true, true, false><<<dim3(3, 64), 256, 0, stream>>>(
        ATT, WoT, Of, nullptr, nullptr, bo, src,
        384, 384, 384, 384, 384);
    // 8. x = LN1(o)
    ln_kernel<<<8192, 128, 0, stream>>>(Of, nullptr, g1, be1, xf, xbf, 0);
    // 9. h = gelu(x @ W1 + b1)
    mgemm128_kernel<2, true, false, true><<<dim3(12, 64), 256, 0, stream>>>(
        xbf, W1T, nullptr, hbf, nullptr, b1, nullptr,
        384, 384, 384, 1536, 0);
    // 10. ff = h @ W2 + b2 + x
    mgemm128_kernel<1, true, true, false><<<dim3(3, 64), 256, 0, stream>>>(
        hbf, W2T, ff, nullptr, nullptr, b2, xf,
        1536, 1536, 1536, 384, 384);
    // 11. out = LN2(ff)
    ln_kernel<<<8192, 128, 0, stream>>>(ff, nullptr, g2, be2, out, nullptr, 0);
}

// Round 18
// 215.705 us; speedup vs baseline: 1.3003x; 1.0542x over previous
//
#include <hip/hip_runtime.h>
#include <math.h>

#define D_MODEL 384
#define HEADS 8
#define DIM_HEAD 48
#define NTOK 1024
#define BATCH 8
#define D_FF 1536
#define LN_EPS 1e-5f

typedef unsigned short u16;
typedef unsigned int u32;
typedef unsigned long long u64;
typedef short short8 __attribute__((ext_vector_type(8)));
typedef float f32x4 __attribute__((ext_vector_type(4)));

union F8 { short8 v; u64 q[2]; u16 u[8]; uint4 u4; };

__device__ __forceinline__ u16 f2bf(float f) {
    union { float f; unsigned u; } c; c.f = f;
    unsigned r = c.u + 0x7FFFu + ((c.u >> 16) & 1u);
    return (u16)(r >> 16);
}
__device__ __forceinline__ float bf2f(u16 u) {
    union { unsigned u; float f; } c; c.u = ((unsigned)u) << 16; return c.f;
}
__device__ __forceinline__ void gload_lds16(const u16* g, u16* l) {
    __builtin_amdgcn_global_load_lds(
        (const __attribute__((address_space(1))) void*)g,
        (__attribute__((address_space(3))) void*)l, 16, 0, 0);
}

// ---------------- add + cast (QKin = bf16(src+pos), SRCB = bf16(src)) ----------------
__global__ __launch_bounds__(256) void add_cast_kernel(
        const float4* __restrict__ a, const float4* __restrict__ b,
        ushort4* __restrict__ o1, ushort4* __restrict__ o2, int n4) {
    int i = blockIdx.x * blockDim.x + threadIdx.x;
    if (i >= n4) return;
    float4 x = a[i], y = b[i];
    ushort4 u1, u2;
    u1.x = f2bf(x.x + y.x); u1.y = f2bf(x.y + y.y); u1.z = f2bf(x.z + y.z); u1.w = f2bf(x.w + y.w);
    u2.x = f2bf(x.x); u2.y = f2bf(x.y); u2.z = f2bf(x.z); u2.w = f2bf(x.w);
    o1[i] = u1; o2[i] = u2;
}

// ---------------- 4x square transpose + cast (384x384), z-batched ----------------
__global__ __launch_bounds__(256) void castT4_kernel(
        const float* __restrict__ i0, const float* __restrict__ i1,
        const float* __restrict__ i2, const float* __restrict__ i3,
        u16* __restrict__ o0, u16* __restrict__ o1,
        u16* __restrict__ o2, u16* __restrict__ o3) {
    const float* in  = (blockIdx.z == 0) ? i0 : (blockIdx.z == 1) ? i1 : (blockIdx.z == 2) ? i2 : i3;
    u16*         out = (blockIdx.z == 0) ? o0 : (blockIdx.z == 1) ? o1 : (blockIdx.z == 2) ? o2 : o3;
    __shared__ float t[32][33];
    int c0 = blockIdx.x * 32, r0 = blockIdx.y * 32;
    int tx = threadIdx.x, ty = threadIdx.y;  // 32 x 8
    for (int i = ty; i < 32; i += 8)
        t[i][tx] = in[(long)(r0 + i) * 384 + c0 + tx];
    __syncthreads();
    for (int i = ty; i < 32; i += 8)
        out[(long)(c0 + i) * 384 + r0 + tx] = f2bf(t[tx][i]);
}

// ---------------- transpose + cast: out[c][r] = bf16(in[r][c]) ----------------
__global__ __launch_bounds__(256) void castT_kernel(
        const float* __restrict__ in, u16* __restrict__ out, int R, int C) {
    __shared__ float t[32][33];
    int c0 = blockIdx.x * 32, r0 = blockIdx.y * 32;
    int tx = threadIdx.x, ty = threadIdx.y;  // 32 x 8
    for (int i = ty; i < 32; i += 8)
        t[i][tx] = in[(long)(r0 + i) * C + c0 + tx];
    __syncthreads();
    for (int i = ty; i < 32; i += 8)
        out[(long)(c0 + i) * R + r0 + tx] = f2bf(t[tx][i]);
}

// ---------------- relative bias, transposed, bf16: BT[h][n][m] = bias[h][m][n] ----------------
__global__ __launch_bounds__(256) void biasT_bf16_kernel(const float* __restrict__ table,
                                                         u16* __restrict__ BT) {
    long i = (long)blockIdx.x * blockDim.x + threadIdx.x;
    const long total = (long)HEADS * NTOK * NTOK;
    if (i >= total) return;
    int m = (int)(i & 1023);
    int n = (int)((i >> 10) & 1023);
    int h = (int)(i >> 20);
    int dy = (m >> 5) - (n >> 5) + 31;
    int dx = (m & 31) - (n & 31) + 31;
    BT[i] = f2bf(table[(dy * 63 + dx) * HEADS + h]);
}

// ---------------- MFMA GEMM, 128x128 tile, double-buffered global_load_lds ----------------
// 1D grid, XCD-swizzled (bijective, NB%8==0): each XCD owns consecutive row-blocks x all
// column-tiles -> A-panels and weights L2-resident per XCD.
// DUAL: blocks with cx >= nxSplit use A2/Bt2/Ct2 (merged Q+K and V projections).
// Counted-vmcnt pipeline with sched_barrier(0) pins (raw s_barrier is not a compiler fence).
// OUTMODE bits: 1 = f32 store, 2 = bf16 store, 8 = head-transposed bf16 store
template<int OUTMODE, bool HAS_BIAS, bool HAS_RES, bool GELU_, bool DUAL>
__global__ __launch_bounds__(256) void mgemm128_kernel(
        const u16* __restrict__ Ab, const u16* __restrict__ Btb,
        const u16* __restrict__ A2, const u16* __restrict__ Bt2,
        float* __restrict__ Cf, u16* __restrict__ Cb,
        u16* __restrict__ Ct, u16* __restrict__ Ct2,
        const float* __restrict__ bias, const float* __restrict__ Rb,
        int Kd, int lda, int ldbt, int ldc, int ldr, int nx, int nxSplit) {
    __shared__ u16 As[2][128 * 32];
    __shared__ u16 Bs[2][128 * 32];
    int tid = threadIdx.x, wave = tid >> 6, lane = tid & 63, g = lane >> 4, l15 = lane & 15;
    int wm = wave >> 1, wn = wave & 1;

    int bid = blockIdx.x;
    int cpx = gridDim.x >> 3;
    int widx = (bid & 7) * cpx + (bid >> 3);   // bijective XCD swizzle
    int ry = widx / nx, cx = widx - ry * nx;
    const u16* Ap = Ab; const u16* Btp = Btb; u16* Ctp = Ct;
    if (DUAL && cx >= nxSplit) { Ap = A2; Btp = Bt2; Ctp = Ct2; cx -= nxSplit; }
    int row0 = ry * 128, col0 = cx * 128;

    f32x4 acc[4][4] = {};

    int sr = lane >> 2, sk = lane & 3;
    const u16* aG0 = Ap  + (long)(row0 + wave * 16 + sr) * lda  + sk * 8;
    const u16* aG1 = Ap  + (long)(row0 + (wave + 4) * 16 + sr) * lda  + sk * 8;
    const u16* bG0 = Btp + (long)(col0 + wave * 16 + sr) * ldbt + sk * 8;
    const u16* bG1 = Btp + (long)(col0 + (wave + 4) * 16 + sr) * ldbt + sk * 8;
    int w0off = (wave * 16) * 32, w1off = ((wave + 4) * 16) * 32;

    const int T = Kd >> 5;
    gload_lds16(aG0, &As[0][w0off]);
    gload_lds16(aG1, &As[0][w1off]);
    gload_lds16(bG0, &Bs[0][w0off]);
    gload_lds16(bG1, &Bs[0][w1off]);
    __builtin_amdgcn_sched_barrier(0);

    for (int t = 0; t < T; ++t) {
        int cur = t & 1, nxt = cur ^ 1;
        if (t + 1 < T) {
            int k1 = (t + 1) << 5;
            gload_lds16(aG0 + k1, &As[nxt][w0off]);
            gload_lds16(aG1 + k1, &As[nxt][w1off]);
            gload_lds16(bG0 + k1, &Bs[nxt][w0off]);
            gload_lds16(bG1 + k1, &Bs[nxt][w1off]);
            __builtin_amdgcn_sched_barrier(0);
            asm volatile("s_waitcnt vmcnt(4)" ::: "memory");  // tile t landed; t+1 in flight
        } else {
            asm volatile("s_waitcnt vmcnt(0)" ::: "memory");
        }
        __builtin_amdgcn_sched_barrier(0);
        __builtin_amdgcn_s_barrier();
        __builtin_amdgcn_sched_barrier(0);
        F8 af[4], bfr[4];
#pragma unroll
        for (int fm = 0; fm < 4; ++fm)
            af[fm].u4 = *(const uint4*)&As[cur][(wm * 64 + fm * 16 + l15) * 32 + g * 8];
#pragma unroll
        for (int fn = 0; fn < 4; ++fn)
            bfr[fn].u4 = *(const uint4*)&Bs[cur][(wn * 64 + fn * 16 + l15) * 32 + g * 8];
#pragma unroll
        for (int fm = 0; fm < 4; ++fm)
#pragma unroll
            for (int fn = 0; fn < 4; ++fn)
                acc[fm][fn] = __builtin_amdgcn_mfma_f32_16x16x32_bf16(
                    af[fm].v, bfr[fn].v, acc[fm][fn], 0, 0, 0);
        __builtin_amdgcn_sched_barrier(0);
        __builtin_amdgcn_s_barrier();   // all waves done reading buf[cur] before re-stage
        __builtin_amdgcn_sched_barrier(0);
    }

#pragma unroll
    for (int fm = 0; fm < 4; ++fm) {
        int rbase = row0 + wm * 64 + fm * 16 + g * 4;
#pragma unroll
        for (int fn = 0; fn < 4; ++fn) {
            int c = col0 + wn * 64 + fn * 16 + l15;
            float bv = HAS_BIAS ? bias[c] : 0.f;
            float vs[4];
#pragma unroll
            for (int r = 0; r < 4; ++r) {
                float v = acc[fm][fn][r] + bv;
                if (HAS_RES) v += Rb[(long)(rbase + r) * ldr + c];
                if (GELU_)   v = 0.5f * v * (1.f + erff(v * 0.70710678118654752f));
                vs[r] = v;
                if (OUTMODE & 1) Cf[(long)(rbase + r) * ldc + c] = v;
                if (OUTMODE & 2) Cb[(long)(rbase + r) * ldc + c] = f2bf(v);
            }
            if (OUTMODE & 8) {
                int hh2 = (c * 683) >> 15; int dd = c - hh2 * 48;   // valid for c < 768
                int bb2 = rbase >> 10;     int mm = rbase & 1023;
                ushort4 o;
                o.x = f2bf(vs[0]); o.y = f2bf(vs[1]); o.z = f2bf(vs[2]); o.w = f2bf(vs[3]);
                *(ushort4*)&Ctp[(long)hh2 * 393216 + (long)(bb2 * 48 + dd) * 1024 + mm] = o;
            }
        }
    }
}

// ---------------- fused bias matmuls -> MFMA-fragment-tiled Q/K/V ----------------
// 1D grid 768, XCD-swizzled (one head per XCD). Double-buffered staging, pinned regions.
__global__ __launch_bounds__(256) void bias3_kernel(
        const u16* __restrict__ BT, const u16* __restrict__ QtH,
        const u16* __restrict__ KtH, const u16* __restrict__ VtH,
        u16* __restrict__ Q2H, u16* __restrict__ K2H, u16* __restrict__ V2T) {
    int bid = blockIdx.x;
    int widx = (bid & 7) * 96 + (bid >> 3);   // bijective (768 % 8 == 0)
    int h = widx / 96;
    int rem = widx - h * 96;
    int ry = rem / 6, cx = rem - ry * 6;
    const long hb = (long)h * 393216;
    const u16* A = BT + (long)h * 1048576;
    __shared__ u16 As[2][64 * 32];
    __shared__ u16 Bq[2][64 * 32], Bk[2][64 * 32], Bv[2][64 * 32];
    int tid = threadIdx.x, wave = tid >> 6, lane = tid & 63, g = lane >> 4, l15 = lane & 15;
    int wm = wave >> 1, wn = wave & 1;
    int row0 = ry * 64, col0 = cx * 64;
    f32x4 acc[3][2][2] = {};

    int sr = lane >> 2, sk = lane & 3;
    const u16* aG = A   + (long)(row0 + wave * 16 + sr) * 1024 + sk * 8;
    const u16* qG = QtH + hb + (long)(col0 + wave * 16 + sr) * 1024 + sk * 8;
    const u16* kG = KtH + hb + (long)(col0 + wave * 16 + sr) * 1024 + sk * 8;
    const u16* vG = VtH + hb + (long)(col0 + wave * 16 + sr) * 1024 + sk * 8;
    int woff = (wave * 16) * 32;

    gload_lds16(aG, &As[0][woff]);
    gload_lds16(qG, &Bq[0][woff]);
    gload_lds16(kG, &Bk[0][woff]);
    gload_lds16(vG, &Bv[0][woff]);
    __builtin_amdgcn_sched_barrier(0);

    for (int t = 0; t < 32; ++t) {
        int cur = t & 1, nxt = cur ^ 1;
        if (t + 1 < 32) {
            int k1 = (t + 1) << 5;
            gload_lds16(aG + k1, &As[nxt][woff]);
            gload_lds16(qG + k1, &Bq[nxt][woff]);
            gload_lds16(kG + k1, &Bk[nxt][woff]);
            gload_lds16(vG + k1, &Bv[nxt][woff]);
            __builtin_amdgcn_sched_barrier(0);
            asm volatile("s_waitcnt vmcnt(4)" ::: "memory");
        } else {
            asm volatile("s_waitcnt vmcnt(0)" ::: "memory");
        }
        __builtin_amdgcn_sched_barrier(0);
        __builtin_amdgcn_s_barrier();
        __builtin_amdgcn_sched_barrier(0);
        F8 af0, af1, b0, b1;
        af0.u4 = *(const uint4*)&As[cur][(wm * 32 + l15) * 32 + g * 8];
        af1.u4 = *(const uint4*)&As[cur][(wm * 32 + 16 + l15) * 32 + g * 8];
        // Q
        b0.u4 = *(const uint4*)&Bq[cur][(wn * 32 + l15) * 32 + g * 8];
        b1.u4 = *(const uint4*)&Bq[cur][(wn * 32 + 16 + l15) * 32 + g * 8];
        acc[0][0][0] = __builtin_amdgcn_mfma_f32_16x16x32_bf16(af0.v, b0.v, acc[0][0][0], 0, 0, 0);
        acc[0][0][1] = __builtin_amdgcn_mfma_f32_16x16x32_bf16(af0.v, b1.v, acc[0][0][1], 0, 0, 0);
        acc[0][1][0] = __builtin_amdgcn_mfma_f32_16x16x32_bf16(af1.v, b0.v, acc[0][1][0], 0, 0, 0);
        acc[0][1][1] = __builtin_amdgcn_mfma_f32_16x16x32_bf16(af1.v, b1.v, acc[0][1][1], 0, 0, 0);
        // K
        b0.u4 = *(const uint4*)&Bk[cur][(wn * 32 + l15) * 32 + g * 8];
        b1.u4 = *(const uint4*)&Bk[cur][(wn * 32 + 16 + l15) * 32 + g * 8];
        acc[1][0][0] = __builtin_amdgcn_mfma_f32_16x16x32_bf16(af0.v, b0.v, acc[1][0][0], 0, 0, 0);
        acc[1][0][1] = __builtin_amdgcn_mfma_f32_16x16x32_bf16(af0.v, b1.v, acc[1][0][1], 0, 0, 0);
        acc[1][1][0] = __builtin_amdgcn_mfma_f32_16x16x32_bf16(af1.v, b0.v, acc[1][1][0], 0, 0, 0);
        acc[1][1][1] = __builtin_amdgcn_mfma_f32_16x16x32_bf16(af1.v, b1.v, acc[1][1][1], 0, 0, 0);
        // V
        b0.u4 = *(const uint4*)&Bv[cur][(wn * 32 + l15) * 32 + g * 8];
        b1.u4 = *(const uint4*)&Bv[cur][(wn * 32 + 16 + l15) * 32 + g * 8];
        acc[2][0][0] = __builtin_amdgcn_mfma_f32_16x16x32_bf16(af0.v, b0.v, acc[2][0][0], 0, 0, 0);
        acc[2][0][1] = __builtin_amdgcn_mfma_f32_16x16x32_bf16(af0.v, b1.v, acc[2][0][1], 0, 0, 0);
        acc[2][1][0] = __builtin_amdgcn_mfma_f32_16x16x32_bf16(af1.v, b0.v, acc[2][1][0], 0, 0, 0);
        acc[2][1][1] = __builtin_amdgcn_mfma_f32_16x16x32_bf16(af1.v, b1.v, acc[2][1][1], 0, 0, 0);
        __builtin_amdgcn_sched_barrier(0);
        __builtin_amdgcn_s_barrier();
        __builtin_amdgcn_sched_barrier(0);
    }

    // Q pre-scale: 48^-0.5 * log2(e)  (attention softmax runs in exp2 domain)
    const float qsc = 0.14433756729740643f * 1.4426950408889634f;
#pragma unroll
    for (int fm = 0; fm < 2; ++fm) {
        int rbase = row0 + wm * 32 + fm * 16 + g * 4;  // token (n for Q/K, m for V)
#pragma unroll
        for (int fn = 0; fn < 2; ++fn) {
            int c = col0 + wn * 32 + fn * 16 + l15;    // 0..383 = b*48+d
            int b2 = (c * 683) >> 15, d = c - b2 * 48;
            long bh = (long)h * 8 + b2;
            ushort4 rq = *(const ushort4*)&QtH[hb + (long)c * 1024 + rbase];
            ushort4 rk = *(const ushort4*)&KtH[hb + (long)c * 1024 + rbase];
            ushort4 rv = *(const ushort4*)&VtH[hb + (long)c * 1024 + rbase];
            const u16* rqa = (const u16*)&rq;
            const u16* rka = (const u16*)&rk;
            const u16* rva = (const u16*)&rv;
            int ks = d >> 5, g3 = (d >> 3) & 3, e = d & 7;
            long qbase = ((bh * 64 + (rbase >> 4)) * 8 + ks * 4 + g3) * 128
                       + (rbase & 15) * 8 + e;
            ushort4 vo;
            u16* voa = (u16*)&vo;
#pragma unroll
            for (int r = 0; r < 4; ++r) {
                float qv = acc[0][fm][fn][r] + bf2f(rqa[r]);
                Q2H[qbase + r * 8] = f2bf(qv * qsc);
                float kv = acc[1][fm][fn][r] + bf2f(rka[r]);
                K2H[qbase + r * 8] = f2bf(kv);
                voa[r] = f2bf(acc[2][fm][fn][r] + bf2f(rva[r]));
            }
            long vaddr = ((((bh * 16 + (rbase >> 6)) * 3 + (d >> 4)) * 2
                          + ((rbase >> 5) & 1)) * 4 + ((rbase >> 3) & 3)) * 128
                       + (d & 15) * 8 + (rbase & 7);
            *(ushort4*)&V2T[vaddr] = vo;
            if (d < 16) {
                long pbase = ((bh * 64 + (rbase >> 4)) * 8 + 4 + 2 + (d >> 3)) * 128
                           + (rbase & 15) * 8 + (d & 7);
#pragma unroll
                for (int r = 0; r < 4; ++r) {
                    Q2H[pbase + r * 8] = 0;
                    K2H[pbase + r * 8] = 0;
                }
            }
        }
    }
}

// ---------------- flash attention, MFMA, bf16, wave-split KV, fragment-tiled ----------------
// 1D grid 4096 XCD-swizzled. (256,4): VGPR 64, no spill (R16-proven stable form).
__global__ __launch_bounds__(256, 4) void attn_mfma_kernel(
        const u16* __restrict__ Q2H, const u16* __restrict__ K2H,
        const u16* __restrict__ V2T, u16* __restrict__ O) {
    int bid = blockIdx.x;
    int widx = (bid & 7) * 512 + (bid >> 3);   // bijective (4096 % 8 == 0)
    int qb = widx & 63;
    int h  = (widx >> 6) & 7;
    int b  = widx >> 9;
    int tid = threadIdx.x, wave = tid >> 6, lane = tid & 63, g = lane >> 4, l15 = lane & 15;

    __shared__ char smem[13824];
    u16   (*Pl)[16][72]  = (u16(*)[16][72])smem;            // [4][16][72] u16 = 9216 B
    float (*Oc)[16][52]  = (float(*)[16][52])smem;          // [4][16][52] f32 = 13312 B
    float (*MLc)[16][2]  = (float(*)[16][2])(smem + 13312); // 512 B
    const int sw = ((l15 >> 3) & 1) << 5;
    const int loff = (g * 16 + l15) * 8;   // fragment lane offset (u16)

    const long bh = (long)(h * 8 + b);
    const u16* qtile = Q2H + (bh * 64 + qb) * 1024;
    F8 qf0, qf1;
    qf0.u4 = *(const uint4*)(qtile + loff);
    qf1.u4 = *(const uint4*)(qtile + 512 + loff);

    f32x4 oacc[3] = {};
    float runm = -1e30f, runl = 0.f;

#pragma unroll
    for (int it = 0; it < 4; ++it) {
        // ---- QK^T for this wave's 64 keys (4 key-tiles of 16) ----
        f32x4 s[4] = {};
#pragma unroll
        for (int mt = 0; mt < 4; ++mt) {
            const u16* ktile = K2H + (bh * 64 + wave * 16 + it * 4 + mt) * 1024;
            F8 kf0, kf1;
            kf0.u4 = *(const uint4*)(ktile + loff);
            kf1.u4 = *(const uint4*)(ktile + 512 + loff);
            s[mt] = __builtin_amdgcn_mfma_f32_16x16x32_bf16(kf0.v, qf0.v, s[mt], 0, 0, 0);
            s[mt] = __builtin_amdgcn_mfma_f32_16x16x32_bf16(kf1.v, qf1.v, s[mt], 0, 0, 0);
        }

        // ---- V fragments (independent; latency hides under softmax) ----
        const u16* vtile = V2T + (bh * 16 + wave * 4 + it) * 3072;
        F8 vf[3][2];
#pragma unroll
        for (int dt = 0; dt < 3; ++dt)
#pragma unroll
            for (int ks = 0; ks < 2; ++ks)
                vf[dt][ks].u4 = *(const uint4*)(vtile + (dt * 2 + ks) * 512 + loff);

        // ---- online softmax (exp2 domain; scale*log2e pre-folded into Q) ----
        float p[16];
#pragma unroll
        for (int i = 0; i < 16; ++i) p[i] = s[i >> 2][i & 3];
        float pm[8];
#pragma unroll
        for (int i = 0; i < 8; ++i) pm[i] = fmaxf(p[i], p[i + 8]);
#pragma unroll
        for (int st = 4; st > 0; st >>= 1)
#pragma unroll
            for (int i = 0; i < st; ++i) pm[i] = fmaxf(pm[i], pm[i + st]);
        float tmax = pm[0];
        tmax = fmaxf(tmax, __shfl_xor(tmax, 16));
        tmax = fmaxf(tmax, __shfl_xor(tmax, 32));
        if (!__all(tmax <= runm + 8.0f)) {     // defer-max (T13)
            float nm = fmaxf(runm, tmax);
            float corr = __builtin_amdgcn_exp2f(runm - nm);
            runm = nm; runl *= corr;
#pragma unroll
            for (int dt = 0; dt < 3; ++dt) {
                oacc[dt][0] *= corr; oacc[dt][1] *= corr;
                oacc[dt][2] *= corr; oacc[dt][3] *= corr;
            }
        }
        float ps = 0.f;
#pragma unroll
        for (int i = 0; i < 16; ++i) { p[i] = __builtin_amdgcn_exp2f(p[i] - runm); ps += p[i]; }
        ps += __shfl_xor(ps, 16);
        ps += __shfl_xor(ps, 32);
        runl += ps;

        // ---- P -> bf16 -> per-wave LDS redistribution ----
#pragma unroll
        for (int mt = 0; mt < 4; ++mt) {
            u32 wa, wb;
            asm("v_cvt_pk_bf16_f32 %0, %1, %2" : "=v"(wa) : "v"(p[mt * 4]), "v"(p[mt * 4 + 1]));
            asm("v_cvt_pk_bf16_f32 %0, %1, %2" : "=v"(wb) : "v"(p[mt * 4 + 2]), "v"(p[mt * 4 + 3]));
            *(u64*)&Pl[wave][l15][(mt * 16 + g * 4) ^ sw] = ((u64)wb << 32) | wa;
        }
        F8 pb[2];
#pragma unroll
        for (int ks = 0; ks < 2; ++ks) {
            pb[ks].q[0] = *(const u64*)&Pl[wave][l15][(ks * 32 + g * 8) ^ sw];
            pb[ks].q[1] = *(const u64*)&Pl[wave][l15][((ks * 32 + g * 8) + 4) ^ sw];
        }

        // ---- PV ----
#pragma unroll
        for (int dt = 0; dt < 3; ++dt) {
            oacc[dt] = __builtin_amdgcn_mfma_f32_16x16x32_bf16(vf[dt][0].v, pb[0].v, oacc[dt], 0, 0, 0);
            oacc[dt] = __builtin_amdgcn_mfma_f32_16x16x32_bf16(vf[dt][1].v, pb[1].v, oacc[dt], 0, 0, 0);
        }
    }

    // ---- cross-wave combine ----
    __syncthreads();   // all waves done with Pl (unioned with Oc)
#pragma unroll
    for (int dt = 0; dt < 3; ++dt)
#pragma unroll
        for (int r = 0; r < 4; ++r)
            Oc[wave][l15][dt * 16 + g * 4 + r] = oacc[dt][r];
    if (g == 0) { MLc[wave][l15][0] = runm; MLc[wave][l15][1] = runl; }
    __syncthreads();

    if (wave == 0) {
        float mm[4], cc[4];
#pragma unroll
        for (int w = 0; w < 4; ++w) mm[w] = MLc[w][l15][0];
        float M = fmaxf(fmaxf(mm[0], mm[1]), fmaxf(mm[2], mm[3]));
        float LL = 0.f;
#pragma unroll
        for (int w = 0; w < 4; ++w) {
            cc[w] = __builtin_amdgcn_exp2f(mm[w] - M);
            LL += cc[w] * MLc[w][l15][1];
        }
        float inv = 1.f / LL;
        u16* op = O + ((long)b * NTOK + qb * 16 + l15) * D_MODEL + h * DIM_HEAD;
#pragma unroll
        for (int dt = 0; dt < 3; ++dt) {
            ushort4 o;
#pragma unroll
            for (int r = 0; r < 4; ++r) {
                int d = dt * 16 + g * 4 + r;
                float v = cc[0] * Oc[0][l15][d] + cc[1] * Oc[1][l15][d]
                        + cc[2] * Oc[2][l15][d] + cc[3] * Oc[3][l15][d];
                ((u16*)&o)[r] = f2bf(v * inv);
            }
            *(ushort4*)(op + dt * 16 + g * 4) = o;
        }
    }
}

// ---------------- layernorm (+optional residual, optional bf16 copy) ----------------
__global__ __launch_bounds__(128) void ln_kernel(
        const float* __restrict__ X, const float* __restrict__ Rb,
        const float* __restrict__ g, const float* __restrict__ be,
        float* __restrict__ O, u16* __restrict__ Obf, int hasRes) {
    int row = blockIdx.x;
    int tid = threadIdx.x;
    const float* x = X + (long)row * D_MODEL;
    float v[3];
#pragma unroll
    for (int l = 0; l < 3; ++l) {
        int c = tid + l * 128;
        v[l] = x[c];
        if (hasRes) v[l] += Rb[(long)row * D_MODEL + c];
    }
    __shared__ float red[128];
    float s = v[0] + v[1] + v[2];
    red[tid] = s; __syncthreads();
    for (int st = 64; st > 0; st >>= 1) {
        if (tid < st) red[tid] += red[tid + st];
        __syncthreads();
    }
    float mean = red[0] * (1.f / 384.f);
    __syncthreads();
    float sq = 0.f;
#pragma unroll
    for (int l = 0; l < 3; ++l) { float d = v[l] - mean; sq += d * d; }
    red[tid] = sq; __syncthreads();
    for (int st = 64; st > 0; st >>= 1) {
        if (tid < st) red[tid] += red[tid + st];
        __syncthreads();
    }
    float rstd = rsqrtf(red[0] * (1.f / 384.f) + LN_EPS);
#pragma unroll
    for (int l = 0; l < 3; ++l) {
        int c = tid + l * 128;
        float o = (v[l] - mean) * rstd * g[c] + be[c];
        O[(long)row * D_MODEL + c] = o;
        if (Obf) Obf[(long)row * D_MODEL + c] = f2bf(o);
    }
}

extern "C" void kernel_launch(void* const* d_in, const int* in_sizes, int n_in,
                              void* d_out, int out_size, void* d_ws, size_t ws_size,
                              hipStream_t stream) {
    const float* src   = (const float*)d_in[0];
    const float* pos   = (const float*)d_in[1];
    const float* table = (const float*)d_in[2];
    const float* Wq  = (const float*)d_in[3];
    const float* Wk  = (const float*)d_in[4];
    const float* Wv  = (const float*)d_in[5];
    const float* Wo  = (const float*)d_in[6];
    const float* bo  = (const float*)d_in[7];
    const float* W1  = (const float*)d_in[8];
    const float* b1  = (const float*)d_in[9];
    const float* W2  = (const float*)d_in[10];
    const float* b2  = (const float*)d_in[11];
    const float* g1  = (const float*)d_in[12];
    const float* be1 = (const float*)d_in[13];
    const float* g2  = (const float*)d_in[14];
    const float* be2 = (const float*)d_in[15];
    float* out = (float*)d_out;
    u16* ws = (u16*)d_ws;

    const long SZ = (long)BATCH * NTOK * D_MODEL;  // 3,145,728

    u16* WqT  = ws + 0;          // WqT,WkT contiguous => merged Q+K projection (Nd=768)
    u16* WkT  = ws + 147456;
    u16* WvT  = ws + 294912;
    u16* WoT  = ws + 442368;
    u16* W1T  = ws + 589824;
    u16* W2T  = ws + 1179648;
    u16* QKin = ws + 1769472;
    u16* SRCB = ws + 4915200;
    u16* QtH  = ws + 8060928;    // [8][384][1024]; KtH contiguous after (merged store target)
    u16* KtH  = ws + 11206656;
    u16* VtH  = ws + 14352384;
    u16* BT   = ws + 17498112;   // [8][1024][1024], dead after bias3
    u16* ATT  = ws + 17498112;   // aliases BT (written by attention, after bias3)
    u16* Q2H  = ws + 25886720;   // frag-tiled [64 bh][64 tb][1024], 4,194,304 u16
    u16* K2H  = ws + 30081024;   // frag-tiled, 4,194,304 u16
    u16* V2T  = ws + 34275328;   // frag-tiled [64 bh][16 mb][3072], 3,145,728 u16 (end 37,421,056)
    // aliases (lifetimes disjoint):
    float* Of  = (float*)(ws + 8060928);   // pre-LN1 f32 (over QtH+KtH, dead after bias3)
    float* xf  = (float*)(ws + 14352384);  // post-LN1 f32 (over VtH + BT head; ATT dead by then)
    u16*   xbf = QKin;                     // post-LN1 bf16 (QKin dead after projections)
    u16*   hbf = Q2H;                      // FF hidden [8192][1536] (over Q2H..V2T, dead by FF1)
    float* ff  = (float*)(ws + 8060928);   // pre-LN2 f32 (over Of, dead after LN1)

    // 1. adds + casts
    add_cast_kernel<<<(int)(SZ / 4 + 255) / 256, 256, 0, stream>>>(
        (const float4*)src, (const float4*)pos, (ushort4*)QKin, (ushort4*)SRCB, (int)(SZ / 4));
    // 2. weight transposes
    dim3 tb(32, 8);
    castT4_kernel<<<dim3(12, 12, 4), tb, 0, stream>>>(Wq, Wk, Wv, Wo, WqT, WkT, WvT, WoT);
    castT_kernel<<<dim3(48, 12), tb, 0, stream>>>(W1, W1T, 384, 1536);
    castT_kernel<<<dim3(12, 48), tb, 0, stream>>>(W2, W2T, 1536, 384);
    // 3. relative bias (transposed, bf16)
    biasT_bf16_kernel<<<32768, 256, 0, stream>>>(table, BT);
    // 4. projections (Q+K merged with V via DUAL), head-major transposed bf16 out.
    //    1D grid 576 = 9 col-tiles x 64 row-blocks, XCD-swizzled.
    mgemm128_kernel<8, false, false, false, true><<<576, 256, 0, stream>>>(
        QKin, WqT, SRCB, WvT, nullptr, nullptr, QtH, VtH, nullptr, nullptr,
        384, 384, 384, 0, 0, 9, 6);
    // 5. fused bias matmuls -> fragment-tiled Q2H (scaled), K2H, V2T
    bias3_kernel<<<768, 256, 0, stream>>>(BT, QtH, KtH, VtH, Q2H, K2H, V2T);
    // 6. attention (wave-split KV, XCD-swizzled, coalesced fragment loads)
    attn_mfma_kernel<<<4096, 256, 0, stream>>>(Q2H, K2H, V2T, ATT);
    // 7. o = att @ Wo + bo + src
    mgemm128_kernel<1, true, true, false, false><<<192, 256, 0, stream>>>(
        ATT, WoT, nullptr, nullptr, Of, nullptr, nullptr, nullptr, bo, src,
        384, 384, 384, 384, 384, 3, 0);
    // 8. x = LN1(o)
    ln_kernel<<<8192, 128, 0, stream>>>(Of, nullptr, g1, be1, xf, xbf, 0);
    // 9. h = gelu(x @ W1 + b1)
    mgemm128_kernel<2, true, false, true, false><<<768, 256, 0, stream>>>(
        xbf, W1T, nullptr, nullptr, nullptr, hbf, nullptr, nullptr, b1, nullptr,
        384, 384, 384, 1536, 0, 12, 0);
    // 10. ff = h @ W2 + b2 + x
    mgemm128_kernel<1, true, true, false, false><<<192, 256, 0, stream>>>(
        hbf, W2T, nullptr, nullptr, ff, nullptr, nullptr, nullptr, b2, xf,
        1536, 1536, 1536, 384, 384, 3, 0);
    // 11. out = LN2(ff)
    ln_kernel<<<8192, 128, 0, stream>>>(ff, nullptr, g2, be2, out, nullptr, 0);
}

// Round 19
// 199.758 us; speedup vs baseline: 1.4041x; 1.0798x over previous
//
#include <hip/hip_runtime.h>
#include <math.h>

#define D_MODEL 384
#define HEADS 8
#define DIM_HEAD 48
#define NTOK 1024
#define BATCH 8
#define D_FF 1536
#define LN_EPS 1e-5f

typedef unsigned short u16;
typedef unsigned int u32;
typedef unsigned long long u64;
typedef short short8 __attribute__((ext_vector_type(8)));
typedef float f32x4 __attribute__((ext_vector_type(4)));

union F8 { short8 v; u64 q[2]; u16 u[8]; uint4 u4; };

__device__ __forceinline__ u16 f2bf(float f) {
    union { float f; unsigned u; } c; c.f = f;
    unsigned r = c.u + 0x7FFFu + ((c.u >> 16) & 1u);
    return (u16)(r >> 16);
}
__device__ __forceinline__ float bf2f(u16 u) {
    union { unsigned u; float f; } c; c.u = ((unsigned)u) << 16; return c.f;
}
__device__ __forceinline__ void gload_lds16(const u16* g, u16* l) {
    __builtin_amdgcn_global_load_lds(
        (const __attribute__((address_space(1))) void*)g,
        (__attribute__((address_space(3))) void*)l, 16, 0, 0);
}

// ---------------- fused prep: add_cast (blocks 0..3071) + biasT x8 (blocks 3072..7167) ----------
__global__ __launch_bounds__(256) void prep_kernel(
        const float4* __restrict__ a, const float4* __restrict__ b,
        ushort4* __restrict__ o1, ushort4* __restrict__ o2,
        const float* __restrict__ table, u16* __restrict__ BT) {
    int bid = blockIdx.x;
    if (bid < 3072) {
        int i = bid * 256 + threadIdx.x;      // n4 = 786432
        float4 x = a[i], y = b[i];
        ushort4 u1, u2;
        u1.x = f2bf(x.x + y.x); u1.y = f2bf(x.y + y.y);
        u1.z = f2bf(x.z + y.z); u1.w = f2bf(x.w + y.w);
        u2.x = f2bf(x.x); u2.y = f2bf(x.y); u2.z = f2bf(x.z); u2.w = f2bf(x.w);
        o1[i] = u1; o2[i] = u2;
    } else {
        // BT[h][n][m] = bf16(table[((ym-yn+31)*63 + (xm-xn+31))*8 + h]), 8 m's per thread
        int i = (bid - 3072) * 256 + threadIdx.x;   // 0..1048575
        long e0 = (long)i * 8;
        int m0 = (int)(e0 & 1023);
        int n  = (int)((e0 >> 10) & 1023);
        int h  = (int)(e0 >> 20);
        int dy = (m0 >> 5) - (n >> 5) + 31;         // m0 8-aligned: dy constant over 8
        int base = (m0 & 31) - (n & 31) + 31;       // dx = base + e
        u16 vals[8];
#pragma unroll
        for (int e = 0; e < 8; ++e)
            vals[e] = f2bf(table[(dy * 63 + base + e) * HEADS + h]);
        uint4 o;
        ((u16*)&o)[0] = vals[0]; ((u16*)&o)[1] = vals[1];
        ((u16*)&o)[2] = vals[2]; ((u16*)&o)[3] = vals[3];
        ((u16*)&o)[4] = vals[4]; ((u16*)&o)[5] = vals[5];
        ((u16*)&o)[6] = vals[6]; ((u16*)&o)[7] = vals[7];
        *(uint4*)&BT[e0] = o;
    }
}

// ---------------- all weight transposes in one launch (1728 tiles) ----------------
// t<576: four 384x384 (144 tiles each); 576..1151: W1 384x1536; 1152..1727: W2 1536x384
__global__ __launch_bounds__(256) void castT_all_kernel(
        const float* __restrict__ Wq, const float* __restrict__ Wk,
        const float* __restrict__ Wv, const float* __restrict__ Wo,
        const float* __restrict__ W1, const float* __restrict__ W2,
        u16* __restrict__ WqT, u16* __restrict__ WkT,
        u16* __restrict__ WvT, u16* __restrict__ WoT,
        u16* __restrict__ W1T, u16* __restrict__ W2T) {
    int t = blockIdx.x;
    const float* in; u16* out; int R, C, cx, ry;
    if (t < 576) {
        int w = t / 144, rem = t - w * 144;
        cx = rem % 12; ry = rem / 12; R = 384; C = 384;
        in  = (w == 0) ? Wq : (w == 1) ? Wk : (w == 2) ? Wv : Wo;
        out = (w == 0) ? WqT : (w == 1) ? WkT : (w == 2) ? WvT : WoT;
    } else if (t < 1152) {
        int rem = t - 576; cx = rem % 48; ry = rem / 48;
        R = 384; C = 1536; in = W1; out = W1T;
    } else {
        int rem = t - 1152; cx = rem % 12; ry = rem / 12;
        R = 1536; C = 384; in = W2; out = W2T;
    }
    __shared__ float tl[32][33];
    int c0 = cx * 32, r0 = ry * 32;
    int tx = threadIdx.x & 31, ty = threadIdx.x >> 5;  // 32 x 8
    for (int i = ty; i < 32; i += 8)
        tl[i][tx] = in[(long)(r0 + i) * C + c0 + tx];
    __syncthreads();
    for (int i = ty; i < 32; i += 8)
        out[(long)(c0 + i) * R + r0 + tx] = f2bf(tl[tx][i]);
}

// ---------------- MFMA GEMM, 128x128 tile, double-buffered global_load_lds ----------------
// 1D grid, XCD-swizzled (bijective, NB%8==0). DUAL: cx >= nxSplit uses A2/Bt2/Ct2.
// Counted-vmcnt pipeline with sched_barrier(0) pins (raw s_barrier is not a compiler fence).
// OUTMODE bits: 1 = f32 store, 2 = bf16 store, 8 = head-transposed bf16 store
template<int OUTMODE, bool HAS_BIAS, bool HAS_RES, bool GELU_, bool DUAL>
__global__ __launch_bounds__(256) void mgemm128_kernel(
        const u16* __restrict__ Ab, const u16* __restrict__ Btb,
        const u16* __restrict__ A2, const u16* __restrict__ Bt2,
        float* __restrict__ Cf, u16* __restrict__ Cb,
        u16* __restrict__ Ct, u16* __restrict__ Ct2,
        const float* __restrict__ bias, const float* __restrict__ Rb,
        int Kd, int lda, int ldbt, int ldc, int ldr, int nx, int nxSplit) {
    __shared__ u16 As[2][128 * 32];
    __shared__ u16 Bs[2][128 * 32];
    int tid = threadIdx.x, wave = tid >> 6, lane = tid & 63, g = lane >> 4, l15 = lane & 15;
    int wm = wave >> 1, wn = wave & 1;

    int bid = blockIdx.x;
    int cpx = gridDim.x >> 3;
    int widx = (bid & 7) * cpx + (bid >> 3);   // bijective XCD swizzle
    int ry = widx / nx, cx = widx - ry * nx;
    const u16* Ap = Ab; const u16* Btp = Btb; u16* Ctp = Ct;
    if (DUAL && cx >= nxSplit) { Ap = A2; Btp = Bt2; Ctp = Ct2; cx -= nxSplit; }
    int row0 = ry * 128, col0 = cx * 128;

    f32x4 acc[4][4] = {};

    int sr = lane >> 2, sk = lane & 3;
    const u16* aG0 = Ap  + (long)(row0 + wave * 16 + sr) * lda  + sk * 8;
    const u16* aG1 = Ap  + (long)(row0 + (wave + 4) * 16 + sr) * lda  + sk * 8;
    const u16* bG0 = Btp + (long)(col0 + wave * 16 + sr) * ldbt + sk * 8;
    const u16* bG1 = Btp + (long)(col0 + (wave + 4) * 16 + sr) * ldbt + sk * 8;
    int w0off = (wave * 16) * 32, w1off = ((wave + 4) * 16) * 32;

    const int T = Kd >> 5;
    gload_lds16(aG0, &As[0][w0off]);
    gload_lds16(aG1, &As[0][w1off]);
    gload_lds16(bG0, &Bs[0][w0off]);
    gload_lds16(bG1, &Bs[0][w1off]);
    __builtin_amdgcn_sched_barrier(0);

    for (int t = 0; t < T; ++t) {
        int cur = t & 1, nxt = cur ^ 1;
        if (t + 1 < T) {
            int k1 = (t + 1) << 5;
            gload_lds16(aG0 + k1, &As[nxt][w0off]);
            gload_lds16(aG1 + k1, &As[nxt][w1off]);
            gload_lds16(bG0 + k1, &Bs[nxt][w0off]);
            gload_lds16(bG1 + k1, &Bs[nxt][w1off]);
            __builtin_amdgcn_sched_barrier(0);
            asm volatile("s_waitcnt vmcnt(4)" ::: "memory");  // tile t landed; t+1 in flight
        } else {
            asm volatile("s_waitcnt vmcnt(0)" ::: "memory");
        }
        __builtin_amdgcn_sched_barrier(0);
        __builtin_amdgcn_s_barrier();
        __builtin_amdgcn_sched_barrier(0);
        F8 af[4], bfr[4];
#pragma unroll
        for (int fm = 0; fm < 4; ++fm)
            af[fm].u4 = *(const uint4*)&As[cur][(wm * 64 + fm * 16 + l15) * 32 + g * 8];
#pragma unroll
        for (int fn = 0; fn < 4; ++fn)
            bfr[fn].u4 = *(const uint4*)&Bs[cur][(wn * 64 + fn * 16 + l15) * 32 + g * 8];
#pragma unroll
        for (int fm = 0; fm < 4; ++fm)
#pragma unroll
            for (int fn = 0; fn < 4; ++fn)
                acc[fm][fn] = __builtin_amdgcn_mfma_f32_16x16x32_bf16(
                    af[fm].v, bfr[fn].v, acc[fm][fn], 0, 0, 0);
        __builtin_amdgcn_sched_barrier(0);
        __builtin_amdgcn_s_barrier();   // all waves done reading buf[cur] before re-stage
        __builtin_amdgcn_sched_barrier(0);
    }

#pragma unroll
    for (int fm = 0; fm < 4; ++fm) {
        int rbase = row0 + wm * 64 + fm * 16 + g * 4;
#pragma unroll
        for (int fn = 0; fn < 4; ++fn) {
            int c = col0 + wn * 64 + fn * 16 + l15;
            float bv = HAS_BIAS ? bias[c] : 0.f;
            float vs[4];
#pragma unroll
            for (int r = 0; r < 4; ++r) {
                float v = acc[fm][fn][r] + bv;
                if (HAS_RES) v += Rb[(long)(rbase + r) * ldr + c];
                if (GELU_)   v = 0.5f * v * (1.f + erff(v * 0.70710678118654752f));
                vs[r] = v;
                if (OUTMODE & 1) Cf[(long)(rbase + r) * ldc + c] = v;
                if (OUTMODE & 2) Cb[(long)(rbase + r) * ldc + c] = f2bf(v);
            }
            if (OUTMODE & 8) {
                int hh2 = (c * 683) >> 15; int dd = c - hh2 * 48;   // valid for c < 768
                int bb2 = rbase >> 10;     int mm = rbase & 1023;
                ushort4 o;
                o.x = f2bf(vs[0]); o.y = f2bf(vs[1]); o.z = f2bf(vs[2]); o.w = f2bf(vs[3]);
                *(ushort4*)&Ctp[(long)hh2 * 393216 + (long)(bb2 * 48 + dd) * 1024 + mm] = o;
            }
        }
    }
}

// ---------------- fused bias matmuls -> MFMA-fragment-tiled Q/K/V ----------------
// 1D grid 768, XCD-swizzled (one head per XCD). Double-buffered staging, pinned regions.
__global__ __launch_bounds__(256) void bias3_kernel(
        const u16* __restrict__ BT, const u16* __restrict__ QtH,
        const u16* __restrict__ KtH, const u16* __restrict__ VtH,
        u16* __restrict__ Q2H, u16* __restrict__ K2H, u16* __restrict__ V2T) {
    int bid = blockIdx.x;
    int widx = (bid & 7) * 96 + (bid >> 3);   // bijective (768 % 8 == 0)
    int h = widx / 96;
    int rem = widx - h * 96;
    int ry = rem / 6, cx = rem - ry * 6;
    const long hb = (long)h * 393216;
    const u16* A = BT + (long)h * 1048576;
    __shared__ u16 As[2][64 * 32];
    __shared__ u16 Bq[2][64 * 32], Bk[2][64 * 32], Bv[2][64 * 32];
    int tid = threadIdx.x, wave = tid >> 6, lane = tid & 63, g = lane >> 4, l15 = lane & 15;
    int wm = wave >> 1, wn = wave & 1;
    int row0 = ry * 64, col0 = cx * 64;
    f32x4 acc[3][2][2] = {};

    int sr = lane >> 2, sk = lane & 3;
    const u16* aG = A   + (long)(row0 + wave * 16 + sr) * 1024 + sk * 8;
    const u16* qG = QtH + hb + (long)(col0 + wave * 16 + sr) * 1024 + sk * 8;
    const u16* kG = KtH + hb + (long)(col0 + wave * 16 + sr) * 1024 + sk * 8;
    const u16* vG = VtH + hb + (long)(col0 + wave * 16 + sr) * 1024 + sk * 8;
    int woff = (wave * 16) * 32;

    gload_lds16(aG, &As[0][woff]);
    gload_lds16(qG, &Bq[0][woff]);
    gload_lds16(kG, &Bk[0][woff]);
    gload_lds16(vG, &Bv[0][woff]);
    __builtin_amdgcn_sched_barrier(0);

    for (int t = 0; t < 32; ++t) {
        int cur = t & 1, nxt = cur ^ 1;
        if (t + 1 < 32) {
            int k1 = (t + 1) << 5;
            gload_lds16(aG + k1, &As[nxt][woff]);
            gload_lds16(qG + k1, &Bq[nxt][woff]);
            gload_lds16(kG + k1, &Bk[nxt][woff]);
            gload_lds16(vG + k1, &Bv[nxt][woff]);
            __builtin_amdgcn_sched_barrier(0);
            asm volatile("s_waitcnt vmcnt(4)" ::: "memory");
        } else {
            asm volatile("s_waitcnt vmcnt(0)" ::: "memory");
        }
        __builtin_amdgcn_sched_barrier(0);
        __builtin_amdgcn_s_barrier();
        __builtin_amdgcn_sched_barrier(0);
        F8 af0, af1, b0, b1;
        af0.u4 = *(const uint4*)&As[cur][(wm * 32 + l15) * 32 + g * 8];
        af1.u4 = *(const uint4*)&As[cur][(wm * 32 + 16 + l15) * 32 + g * 8];
        // Q
        b0.u4 = *(const uint4*)&Bq[cur][(wn * 32 + l15) * 32 + g * 8];
        b1.u4 = *(const uint4*)&Bq[cur][(wn * 32 + 16 + l15) * 32 + g * 8];
        acc[0][0][0] = __builtin_amdgcn_mfma_f32_16x16x32_bf16(af0.v, b0.v, acc[0][0][0], 0, 0, 0);
        acc[0][0][1] = __builtin_amdgcn_mfma_f32_16x16x32_bf16(af0.v, b1.v, acc[0][0][1], 0, 0, 0);
        acc[0][1][0] = __builtin_amdgcn_mfma_f32_16x16x32_bf16(af1.v, b0.v, acc[0][1][0], 0, 0, 0);
        acc[0][1][1] = __builtin_amdgcn_mfma_f32_16x16x32_bf16(af1.v, b1.v, acc[0][1][1], 0, 0, 0);
        // K
        b0.u4 = *(const uint4*)&Bk[cur][(wn * 32 + l15) * 32 + g * 8];
        b1.u4 = *(const uint4*)&Bk[cur][(wn * 32 + 16 + l15) * 32 + g * 8];
        acc[1][0][0] = __builtin_amdgcn_mfma_f32_16x16x32_bf16(af0.v, b0.v, acc[1][0][0], 0, 0, 0);
        acc[1][0][1] = __builtin_amdgcn_mfma_f32_16x16x32_bf16(af0.v, b1.v, acc[1][0][1], 0, 0, 0);
        acc[1][1][0] = __builtin_amdgcn_mfma_f32_16x16x32_bf16(af1.v, b0.v, acc[1][1][0], 0, 0, 0);
        acc[1][1][1] = __builtin_amdgcn_mfma_f32_16x16x32_bf16(af1.v, b1.v, acc[1][1][1], 0, 0, 0);
        // V
        b0.u4 = *(const uint4*)&Bv[cur][(wn * 32 + l15) * 32 + g * 8];
        b1.u4 = *(const uint4*)&Bv[cur][(wn * 32 + 16 + l15) * 32 + g * 8];
        acc[2][0][0] = __builtin_amdgcn_mfma_f32_16x16x32_bf16(af0.v, b0.v, acc[2][0][0], 0, 0, 0);
        acc[2][0][1] = __builtin_amdgcn_mfma_f32_16x16x32_bf16(af0.v, b1.v, acc[2][0][1], 0, 0, 0);
        acc[2][1][0] = __builtin_amdgcn_mfma_f32_16x16x32_bf16(af1.v, b0.v, acc[2][1][0], 0, 0, 0);
        acc[2][1][1] = __builtin_amdgcn_mfma_f32_16x16x32_bf16(af1.v, b1.v, acc[2][1][1], 0, 0, 0);
        __builtin_amdgcn_sched_barrier(0);
        __builtin_amdgcn_s_barrier();
        __builtin_amdgcn_sched_barrier(0);
    }

    // Q pre-scale: 48^-0.5 * log2(e)  (attention softmax runs in exp2 domain)
    const float qsc = 0.14433756729740643f * 1.4426950408889634f;
#pragma unroll
    for (int fm = 0; fm < 2; ++fm) {
        int rbase = row0 + wm * 32 + fm * 16 + g * 4;  // token (n for Q/K, m for V)
#pragma unroll
        for (int fn = 0; fn < 2; ++fn) {
            int c = col0 + wn * 32 + fn * 16 + l15;    // 0..383 = b*48+d
            int b2 = (c * 683) >> 15, d = c - b2 * 48;
            long bh = (long)h * 8 + b2;
            ushort4 rq = *(const ushort4*)&QtH[hb + (long)c * 1024 + rbase];
            ushort4 rk = *(const ushort4*)&KtH[hb + (long)c * 1024 + rbase];
            ushort4 rv = *(const ushort4*)&VtH[hb + (long)c * 1024 + rbase];
            const u16* rqa = (const u16*)&rq;
            const u16* rka = (const u16*)&rk;
            const u16* rva = (const u16*)&rv;
            int ks = d >> 5, g3 = (d >> 3) & 3, e = d & 7;
            long qbase = ((bh * 64 + (rbase >> 4)) * 8 + ks * 4 + g3) * 128
                       + (rbase & 15) * 8 + e;
            ushort4 vo;
            u16* voa = (u16*)&vo;
#pragma unroll
            for (int r = 0; r < 4; ++r) {
                float qv = acc[0][fm][fn][r] + bf2f(rqa[r]);
                Q2H[qbase + r * 8] = f2bf(qv * qsc);
                float kv = acc[1][fm][fn][r] + bf2f(rka[r]);
                K2H[qbase + r * 8] = f2bf(kv);
                voa[r] = f2bf(acc[2][fm][fn][r] + bf2f(rva[r]));
            }
            long vaddr = ((((bh * 16 + (rbase >> 6)) * 3 + (d >> 4)) * 2
                          + ((rbase >> 5) & 1)) * 4 + ((rbase >> 3) & 3)) * 128
                       + (d & 15) * 8 + (rbase & 7);
            *(ushort4*)&V2T[vaddr] = vo;
            if (d < 16) {
                long pbase = ((bh * 64 + (rbase >> 4)) * 8 + 4 + 2 + (d >> 3)) * 128
                           + (rbase & 15) * 8 + (d & 7);
#pragma unroll
                for (int r = 0; r < 4; ++r) {
                    Q2H[pbase + r * 8] = 0;
                    K2H[pbase + r * 8] = 0;
                }
            }
        }
    }
}

// ---------------- flash attention, MFMA, bf16, wave-split KV, fragment-tiled ----------------
// 1D grid 4096 XCD-swizzled. (256,4): VGPR 64, no spill (R16-proven stable form).
__global__ __launch_bounds__(256, 4) void attn_mfma_kernel(
        const u16* __restrict__ Q2H, const u16* __restrict__ K2H,
        const u16* __restrict__ V2T, u16* __restrict__ O) {
    int bid = blockIdx.x;
    int widx = (bid & 7) * 512 + (bid >> 3);   // bijective (4096 % 8 == 0)
    int qb = widx & 63;
    int h  = (widx >> 6) & 7;
    int b  = widx >> 9;
    int tid = threadIdx.x, wave = tid >> 6, lane = tid & 63, g = lane >> 4, l15 = lane & 15;

    __shared__ char smem[13824];
    u16   (*Pl)[16][72]  = (u16(*)[16][72])smem;            // [4][16][72] u16 = 9216 B
    float (*Oc)[16][52]  = (float(*)[16][52])smem;          // [4][16][52] f32 = 13312 B
    float (*MLc)[16][2]  = (float(*)[16][2])(smem + 13312); // 512 B
    const int sw = ((l15 >> 3) & 1) << 5;
    const int loff = (g * 16 + l15) * 8;   // fragment lane offset (u16)

    const long bh = (long)(h * 8 + b);
    const u16* qtile = Q2H + (bh * 64 + qb) * 1024;
    F8 qf0, qf1;
    qf0.u4 = *(const uint4*)(qtile + loff);
    qf1.u4 = *(const uint4*)(qtile + 512 + loff);

    f32x4 oacc[3] = {};
    float runm = -1e30f, runl = 0.f;

#pragma unroll
    for (int it = 0; it < 4; ++it) {
        // ---- QK^T for this wave's 64 keys (4 key-tiles of 16) ----
        f32x4 s[4] = {};
#pragma unroll
        for (int mt = 0; mt < 4; ++mt) {
            const u16* ktile = K2H + (bh * 64 + wave * 16 + it * 4 + mt) * 1024;
            F8 kf0, kf1;
            kf0.u4 = *(const uint4*)(ktile + loff);
            kf1.u4 = *(const uint4*)(ktile + 512 + loff);
            s[mt] = __builtin_amdgcn_mfma_f32_16x16x32_bf16(kf0.v, qf0.v, s[mt], 0, 0, 0);
            s[mt] = __builtin_amdgcn_mfma_f32_16x16x32_bf16(kf1.v, qf1.v, s[mt], 0, 0, 0);
        }

        // ---- V fragments (independent; latency hides under softmax) ----
        const u16* vtile = V2T + (bh * 16 + wave * 4 + it) * 3072;
        F8 vf[3][2];
#pragma unroll
        for (int dt = 0; dt < 3; ++dt)
#pragma unroll
            for (int ks = 0; ks < 2; ++ks)
                vf[dt][ks].u4 = *(const uint4*)(vtile + (dt * 2 + ks) * 512 + loff);

        // ---- online softmax (exp2 domain; scale*log2e pre-folded into Q) ----
        float p[16];
#pragma unroll
        for (int i = 0; i < 16; ++i) p[i] = s[i >> 2][i & 3];
        float pm[8];
#pragma unroll
        for (int i = 0; i < 8; ++i) pm[i] = fmaxf(p[i], p[i + 8]);
#pragma unroll
        for (int st = 4; st > 0; st >>= 1)
#pragma unroll
            for (int i = 0; i < st; ++i) pm[i] = fmaxf(pm[i], pm[i + st]);
        float tmax = pm[0];
        tmax = fmaxf(tmax, __shfl_xor(tmax, 16));
        tmax = fmaxf(tmax, __shfl_xor(tmax, 32));
        if (!__all(tmax <= runm + 8.0f)) {     // defer-max (T13)
            float nm = fmaxf(runm, tmax);
            float corr = __builtin_amdgcn_exp2f(runm - nm);
            runm = nm; runl *= corr;
#pragma unroll
            for (int dt = 0; dt < 3; ++dt) {
                oacc[dt][0] *= corr; oacc[dt][1] *= corr;
                oacc[dt][2] *= corr; oacc[dt][3] *= corr;
            }
        }
        float ps = 0.f;
#pragma unroll
        for (int i = 0; i < 16; ++i) { p[i] = __builtin_amdgcn_exp2f(p[i] - runm); ps += p[i]; }
        ps += __shfl_xor(ps, 16);
        ps += __shfl_xor(ps, 32);
        runl += ps;

        // ---- P -> bf16 -> per-wave LDS redistribution ----
#pragma unroll
        for (int mt = 0; mt < 4; ++mt) {
            u32 wa, wb;
            asm("v_cvt_pk_bf16_f32 %0, %1, %2" : "=v"(wa) : "v"(p[mt * 4]), "v"(p[mt * 4 + 1]));
            asm("v_cvt_pk_bf16_f32 %0, %1, %2" : "=v"(wb) : "v"(p[mt * 4 + 2]), "v"(p[mt * 4 + 3]));
            *(u64*)&Pl[wave][l15][(mt * 16 + g * 4) ^ sw] = ((u64)wb << 32) | wa;
        }
        F8 pb[2];
#pragma unroll
        for (int ks = 0; ks < 2; ++ks) {
            pb[ks].q[0] = *(const u64*)&Pl[wave][l15][(ks * 32 + g * 8) ^ sw];
            pb[ks].q[1] = *(const u64*)&Pl[wave][l15][((ks * 32 + g * 8) + 4) ^ sw];
        }

        // ---- PV ----
#pragma unroll
        for (int dt = 0; dt < 3; ++dt) {
            oacc[dt] = __builtin_amdgcn_mfma_f32_16x16x32_bf16(vf[dt][0].v, pb[0].v, oacc[dt], 0, 0, 0);
            oacc[dt] = __builtin_amdgcn_mfma_f32_16x16x32_bf16(vf[dt][1].v, pb[1].v, oacc[dt], 0, 0, 0);
        }
    }

    // ---- cross-wave combine ----
    __syncthreads();   // all waves done with Pl (unioned with Oc)
#pragma unroll
    for (int dt = 0; dt < 3; ++dt)
#pragma unroll
        for (int r = 0; r < 4; ++r)
            Oc[wave][l15][dt * 16 + g * 4 + r] = oacc[dt][r];
    if (g == 0) { MLc[wave][l15][0] = runm; MLc[wave][l15][1] = runl; }
    __syncthreads();

    if (wave == 0) {
        float mm[4], cc[4];
#pragma unroll
        for (int w = 0; w < 4; ++w) mm[w] = MLc[w][l15][0];
        float M = fmaxf(fmaxf(mm[0], mm[1]), fmaxf(mm[2], mm[3]));
        float LL = 0.f;
#pragma unroll
        for (int w = 0; w < 4; ++w) {
            cc[w] = __builtin_amdgcn_exp2f(mm[w] - M);
            LL += cc[w] * MLc[w][l15][1];
        }
        float inv = 1.f / LL;
        u16* op = O + ((long)b * NTOK + qb * 16 + l15) * D_MODEL + h * DIM_HEAD;
#pragma unroll
        for (int dt = 0; dt < 3; ++dt) {
            ushort4 o;
#pragma unroll
            for (int r = 0; r < 4; ++r) {
                int d = dt * 16 + g * 4 + r;
                float v = cc[0] * Oc[0][l15][d] + cc[1] * Oc[1][l15][d]
                        + cc[2] * Oc[2][l15][d] + cc[3] * Oc[3][l15][d];
                ((u16*)&o)[r] = f2bf(v * inv);
            }
            *(ushort4*)(op + dt * 16 + g * 4) = o;
        }
    }
}

// ---------------- layernorm (+optional residual, optional bf16 copy) ----------------
__global__ __launch_bounds__(128) void ln_kernel(
        const float* __restrict__ X, const float* __restrict__ Rb,
        const float* __restrict__ g, const float* __restrict__ be,
        float* __restrict__ O, u16* __restrict__ Obf, int hasRes) {
    int row = blockIdx.x;
    int tid = threadIdx.x;
    const float* x = X + (long)row * D_MODEL;
    float v[3];
#pragma unroll
    for (int l = 0; l < 3; ++l) {
        int c = tid + l * 128;
        v[l] = x[c];
        if (hasRes) v[l] += Rb[(long)row * D_MODEL + c];
    }
    __shared__ float red[128];
    float s = v[0] + v[1] + v[2];
    red[tid] = s; __syncthreads();
    for (int st = 64; st > 0; st >>= 1) {
        if (tid < st) red[tid] += red[tid + st];
        __syncthreads();
    }
    float mean = red[0] * (1.f / 384.f);
    __syncthreads();
    float sq = 0.f;
#pragma unroll
    for (int l = 0; l < 3; ++l) { float d = v[l] - mean; sq += d * d; }
    red[tid] = sq; __syncthreads();
    for (int st = 64; st > 0; st >>= 1) {
        if (tid < st) red[tid] += red[tid + st];
        __syncthreads();
    }
    float rstd = rsqrtf(red[0] * (1.f / 384.f) + LN_EPS);
#pragma unroll
    for (int l = 0; l < 3; ++l) {
        int c = tid + l * 128;
        float o = (v[l] - mean) * rstd * g[c] + be[c];
        O[(long)row * D_MODEL + c] = o;
        if (Obf) Obf[(long)row * D_MODEL + c] = f2bf(o);
    }
}

extern "C" void kernel_launch(void* const* d_in, const int* in_sizes, int n_in,
                              void* d_out, int out_size, void* d_ws, size_t ws_size,
                              hipStream_t stream) {
    const float* src   = (const float*)d_in[0];
    const float* pos   = (const float*)d_in[1];
    const float* table = (const float*)d_in[2];
    const float* Wq  = (const float*)d_in[3];
    const float* Wk  = (const float*)d_in[4];
    const float* Wv  = (const float*)d_in[5];
    const float* Wo  = (const float*)d_in[6];
    const float* bo  = (const float*)d_in[7];
    const float* W1  = (const float*)d_in[8];
    const float* b1  = (const float*)d_in[9];
    const float* W2  = (const float*)d_in[10];
    const float* b2  = (const float*)d_in[11];
    const float* g1  = (const float*)d_in[12];
    const float* be1 = (const float*)d_in[13];
    const float* g2  = (const float*)d_in[14];
    const float* be2 = (const float*)d_in[15];
    float* out = (float*)d_out;
    u16* ws = (u16*)d_ws;

    const long SZ = (long)BATCH * NTOK * D_MODEL;  // 3,145,728

    u16* WqT  = ws + 0;          // WqT,WkT contiguous => merged Q+K projection (Nd=768)
    u16* WkT  = ws + 147456;
    u16* WvT  = ws + 294912;
    u16* WoT  = ws + 442368;
    u16* W1T  = ws + 589824;
    u16* W2T  = ws + 1179648;
    u16* QKin = ws + 1769472;
    u16* SRCB = ws + 4915200;
    u16* QtH  = ws + 8060928;    // [8][384][1024]; KtH contiguous after (merged store target)
    u16* KtH  = ws + 11206656;
    u16* VtH  = ws + 14352384;
    u16* BT   = ws + 17498112;   // [8][1024][1024], dead after bias3
    u16* ATT  = ws + 17498112;   // aliases BT (written by attention, after bias3)
    u16* Q2H  = ws + 25886720;   // frag-tiled [64 bh][64 tb][1024], 4,194,304 u16
    u16* K2H  = ws + 30081024;   // frag-tiled, 4,194,304 u16
    u16* V2T  = ws + 34275328;   // frag-tiled [64 bh][16 mb][3072], 3,145,728 u16 (end 37,421,056)
    // aliases (lifetimes disjoint):
    float* Of  = (float*)(ws + 8060928);   // pre-LN1 f32 (over QtH+KtH, dead after bias3)
    float* xf  = (float*)(ws + 14352384);  // post-LN1 f32 (over VtH + BT head; ATT dead by then)
    u16*   xbf = QKin;                     // post-LN1 bf16 (QKin dead after projections)
    u16*   hbf = Q2H;                      // FF hidden [8192][1536] (over Q2H..V2T, dead by FF1)
    float* ff  = (float*)(ws + 8060928);   // pre-LN2 f32 (over Of, dead after LN1)

    // 1. fused prep: adds+casts plus relative-bias table expansion (one launch)
    prep_kernel<<<7168, 256, 0, stream>>>(
        (const float4*)src, (const float4*)pos, (ushort4*)QKin, (ushort4*)SRCB, table, BT);
    // 2. all weight transposes (one launch)
    castT_all_kernel<<<1728, 256, 0, stream>>>(
        Wq, Wk, Wv, Wo, W1, W2, WqT, WkT, WvT, WoT, W1T, W2T);
    // 3. projections (Q+K merged with V via DUAL), head-major transposed bf16 out.
    mgemm128_kernel<8, false, false, false, true><<<576, 256, 0, stream>>>(
        QKin, WqT, SRCB, WvT, nullptr, nullptr, QtH, VtH, nullptr, nullptr,
        384, 384, 384, 0, 0, 9, 6);
    // 4. fused bias matmuls -> fragment-tiled Q2H (scaled), K2H, V2T
    bias3_kernel<<<768, 256, 0, stream>>>(BT, QtH, KtH, VtH, Q2H, K2H, V2T);
    // 5. attention (wave-split KV, XCD-swizzled, coalesced fragment loads)
    attn_mfma_kernel<<<4096, 256, 0, stream>>>(Q2H, K2H, V2T, ATT);
    // 6. o = att @ Wo + bo + src
    mgemm128_kernel<1, true, true, false, false><<<192, 256, 0, stream>>>(
        ATT, WoT, nullptr, nullptr, Of, nullptr, nullptr, nullptr, bo, src,
        384, 384, 384, 384, 384, 3, 0);
    // 7. x = LN1(o)
    ln_kernel<<<8192, 128, 0, stream>>>(Of, nullptr, g1, be1, xf, xbf, 0);
    // 8. h = gelu(x @ W1 + b1)
    mgemm128_kernel<2, true, false, true, false><<<768, 256, 0, stream>>>(
        xbf, W1T, nullptr, nullptr, nullptr, hbf, nullptr, nullptr, b1, nullptr,
        384, 384, 384, 1536, 0, 12, 0);
    // 9. ff = h @ W2 + b2 + x
    mgemm128_kernel<1, true, true, false, false><<<192, 256, 0, stream>>>(
        hbf, W2T, nullptr, nullptr, ff, nullptr, nullptr, nullptr, b2, xf,
        1536, 1536, 1536, 384, 384, 3, 0);
    // 10. out = LN2(ff)
    ln_kernel<<<8192, 128, 0, stream>>>(ff, nullptr, g2, be2, out, nullptr, 0);
}